// Round 3
// baseline (591.775 us; speedup 1.0000x reference)
//
#include <hip/hip_runtime.h>

typedef __bf16 bf16x8 __attribute__((ext_vector_type(8)));
typedef __bf16 bf16x4 __attribute__((ext_vector_type(4)));
typedef float  f32x4  __attribute__((ext_vector_type(4)));

__device__ __forceinline__ bf16x8 ldb8(const __bf16* p) {
    return *reinterpret_cast<const bf16x8*>(p);
}
__device__ __forceinline__ bf16x8 zero8() {
    bf16x8 z;
    #pragma unroll
    for (int i = 0; i < 8; i++) z[i] = (__bf16)0.f;
    return z;
}
// mode m: 0 = storage is bf16, 1 = storage is fp32
__device__ __forceinline__ __bf16 ldw(const void* p, int i, int m) {
    return m ? (__bf16)((const float*)p)[i] : ((const __bf16*)p)[i];
}
__device__ __forceinline__ bf16x8 ldx8(const void* p, size_t ei, int m) {
    if (m) {
        const float* f = (const float*)p + ei;
        f32x4 a = *reinterpret_cast<const f32x4*>(f);
        f32x4 b = *reinterpret_cast<const f32x4*>(f + 4);
        bf16x8 r;
        #pragma unroll
        for (int u = 0; u < 4; u++) { r[u] = (__bf16)a[u]; r[4 + u] = (__bf16)b[u]; }
        return r;
    }
    return ldb8((const __bf16*)p + ei);
}

// ---------------- detect: input dtype + packed mask bits (64 blocks) ----------------
// maskb: [256 b][6 u32] bitmask; bits >=164 pre-set (masked).
__global__ __launch_bounds__(256) void detect_kernel(
    const void* x, const void* mask, int* modes, unsigned* maskb)
{
    __shared__ int v32bad, v16bad, sbad;
    __shared__ unsigned mb[24];
    const int t = threadIdx.x, bid = blockIdx.x;
    if (t == 0) { v32bad = 0; v16bad = 0; sbad = 0; }
    if (t < 24) mb[t] = ((t % 6) == 5) ? 0xFFFFFFF0u : 0u;
    __syncthreads();
    const unsigned int* mw = (const unsigned int*)mask;
    int b32 = 0, b16 = 0;
    for (int i = t; i < 10496; i += 256) {
        unsigned int w = mw[i];
        if (!(w == 0u || w == 1u || w == 0x3F800000u)) b32++;
        unsigned int h0 = w & 0xFFFFu, h1 = w >> 16;
        if (!(h0 == 0u || h0 == 1u || h0 == 0x3F80u)) b16++;
        if (!(h1 == 0u || h1 == 1u || h1 == 0x3F80u)) b16++;
    }
    if (b32) atomicAdd(&v32bad, b32);
    if (b16) atomicAdd(&v16bad, b16);
    if (bid == 0) {
        const unsigned int* xw = (const unsigned int*)x;
        int bad = 0;
        for (int i = t; i < 2048; i += 256) {
            unsigned int w = xw[i];
            unsigned int el = (w >> 7) & 0xFF, eh = (w >> 23) & 0xFF;
            if (el >= 0x94 || el == 0xFF) bad++;
            if (eh >= 0x94 || eh == 0xFF) bad++;
        }
        if (bad) atomicAdd(&sbad, bad);
    }
    __syncthreads();
    const int mmode = (v32bad == 0) ? 0 : ((v16bad == 0) ? 2 : 1);
    if (bid == 0 && t == 0) { modes[0] = (sbad > 64) ? 1 : 0; modes[1] = mmode; }
    // this block owns batches bid*4 .. bid*4+3  (4*164 = 656 mask entries)
    const int lo = bid * 656;
    for (int i2 = t; i2 < 656; i2 += 256) {
        int i = lo + i2;
        int val;
        if (mmode == 0)      val = (((const int*)mask)[i] != 0);
        else if (mmode == 2) val = (((const unsigned short*)mask)[i] != 0);
        else                 val = (((const unsigned char*)mask)[i] != 0);
        if (val) {
            int ib = i2 / 164, jb = i2 - ib * 164;
            atomicOr(&mb[ib * 6 + (jb >> 5)], 1u << (jb & 31));
        }
    }
    __syncthreads();
    if (t < 24) maskb[bid * 24 + t] = mb[t];
}

// ---------------- prep: transpose/pad weights into ws (mode-aware) ----------------
// Bias fold: w1t[n][k==100] = b1[n]; w2t[n][k==50] = b2[n]  (augmented GEMM).
__global__ __launch_bounds__(256) void prep_kernel(
    const void* wqks, const void* wqkq, const void* wv, const void* w1,
    const void* w2, const void* wout, const void* wg, const void* bg,
    const void* lng, const void* lnb, const void* b1, const void* b2,
    const void* bout, const int* __restrict__ modes,
    __bf16* __restrict__ Wts, __bf16* __restrict__ Wtq,
    __bf16* __restrict__ w1t, __bf16* __restrict__ w2t,
    __bf16* __restrict__ wot, __bf16* __restrict__ wsm)
{
    const int m = modes[0];
    int i = blockIdx.x * 256 + threadIdx.x;
    if (i < 196608) {
        int n = i >> 8, k = i & 255;
        __bf16 vs, vq;
        if (n < 512) { vs = ldw(wqks, k * 512 + n, m); vq = ldw(wqkq, k * 512 + n, m); }
        else         { vs = ldw(wv, k * 256 + (n - 512), m); vq = vs; }
        Wts[i] = vs; Wtq[i] = vq;
        return;
    }
    i -= 196608;
    if (i < 32768) {
        int e = i >> 13, r = i & 8191, n = r >> 7, k = r & 127;
        __bf16 v = (__bf16)0.f;
        if (n < 50) {
            if (k < 100)       v = ldw(w1, (e * 100 + k) * 50 + n, m);
            else if (k == 100) v = ldw(b1, e * 50 + n, m);
        }
        w1t[i] = v;
        return;
    }
    i -= 32768;
    if (i < 28672) {
        int e = i / 7168, r = i % 7168, n = r >> 6, k = r & 63;
        __bf16 v = (__bf16)0.f;
        if (n < 100) {
            if (k < 50)       v = ldw(w2, (e * 50 + k) * 100 + n, m);
            else if (k == 50) v = ldw(b2, e * 100 + n, m);
        }
        w2t[i] = v;
        return;
    }
    i -= 28672;
    if (i < 65536) {
        int n = i >> 8, k = i & 255;
        wot[i] = ldw(wout, k * 256 + n, m);
        return;
    }
    i -= 65536;
    if (i < 996) {
        __bf16 v;
        if (i < 128)      v = ldw(wg, i, m);
        else if (i < 132) v = ldw(bg, i - 128, m);
        else if (i < 136) v = ldw(lng, i - 132, m);
        else if (i < 140) v = ldw(lnb, i - 136, m);
        else if (i < 340) v = ldw(b1, i - 140, m);
        else if (i < 740) v = ldw(b2, i - 340, m);
        else              v = ldw(bout, i - 740, m);
        wsm[i] = v;
    }
}

// ---------------- qkv projection GEMM + fused gate ----------------
// grid (12, B). q/k tiles use swapped operands mfma(W,x) so each lane holds
// 4 consecutive channels -> bf16x4 stores. V tiles keep mfma(x,W) -> bf16x4 on i.
__global__ __launch_bounds__(256, 2) void qkv_kernel(
    const void* __restrict__ x, const __bf16* __restrict__ Wts,
    const __bf16* __restrict__ Wtq, const __bf16* __restrict__ wsm,
    const int* __restrict__ modes,
    __bf16* __restrict__ q, __bf16* __restrict__ k, __bf16* __restrict__ vt,
    float* __restrict__ gates)
{
    __shared__ __bf16 xs[32][264];
    __shared__ float wgf[128];
    __shared__ float gcst[12];
    const int m = modes[0];
    const int b = blockIdx.y;
    const int mt = blockIdx.x >> 1;
    const int half = blockIdx.x & 1;
    const __bf16* Wt = (mt < 4) ? Wts : Wtq;
    const int rbase = (mt < 4) ? mt * 32 : 100 + (mt - 4) * 32;
    const int tid = threadIdx.x;

    if (tid < 128) wgf[tid] = (float)wsm[tid];
    if (tid < 12)  gcst[tid] = (float)wsm[128 + tid];
    for (int c = tid; c < 1024; c += 256) {
        int row = c >> 5, part = c & 31;
        bf16x8 val = ldx8(x, ((size_t)b * 164 + rbase + row) * 256 + part * 8, m);
        *reinterpret_cast<bf16x8*>(&xs[row][part * 8]) = val;
    }
    __syncthreads();

    // ---- fused gate (only half==0 computes) ----
    if (half == 0) {
        int jg = rbase * 8 + tid;
        int h = jg / 164;
        int j = jg - h * 164;
        if (j < 100) {
            const __bf16* xp = &xs[tid >> 3][(tid & 7) * 32];
            float g[4] = {gcst[0], gcst[1], gcst[2], gcst[3]};
            #pragma unroll
            for (int p = 0; p < 4; p++) {
                bf16x8 xv = ldb8(xp + p * 8);
                #pragma unroll
                for (int u = 0; u < 8; u++) {
                    float f = (float)xv[u];
                    #pragma unroll
                    for (int e = 0; e < 4; e++) g[e] += f * wgf[(p * 8 + u) * 4 + e];
                }
            }
            float mu = 0.25f * (g[0] + g[1] + g[2] + g[3]);
            float var = 0.25f * ((g[0]-mu)*(g[0]-mu) + (g[1]-mu)*(g[1]-mu) +
                                 (g[2]-mu)*(g[2]-mu) + (g[3]-mu)*(g[3]-mu));
            float is = rsqrtf(var + 1e-5f);
            float mx = -3.0e38f;
            #pragma unroll
            for (int e = 0; e < 4; e++) {
                g[e] = (g[e] - mu) * is * gcst[4 + e] + gcst[8 + e];
                mx = fmaxf(mx, g[e]);
            }
            float s = 0.f;
            #pragma unroll
            for (int e = 0; e < 4; e++) { g[e] = __expf(g[e] - mx); s += g[e]; }
            float inv = 1.f / s;
            float4 gv = make_float4(g[0]*inv, g[1]*inv, g[2]*inv, g[3]*inv);
            *reinterpret_cast<float4*>(&gates[((size_t)(b * 8 + h) * 100 + j) * 4]) = gv;
        }
    }

    const int w = tid >> 6, l = tid & 63, lr = l & 15, lc = l >> 4;
    const int c0 = half * 384 + w * 96;    // wave channel base
    f32x4 acc[2][6];
    #pragma unroll
    for (int ms = 0; ms < 2; ms++)
        #pragma unroll
        for (int nt = 0; nt < 6; nt++) acc[ms][nt] = (f32x4){0.f, 0.f, 0.f, 0.f};

    #pragma unroll
    for (int kt = 0; kt < 8; kt++) {
        bf16x8 bx0 = ldb8(&xs[lr][kt * 32 + lc * 8]);
        bf16x8 bx1 = ldb8(&xs[16 + lr][kt * 32 + lc * 8]);
        #pragma unroll
        for (int nt = 0; nt < 6; nt++) {
            bf16x8 aw = ldb8(Wt + (size_t)(c0 + nt * 16 + lr) * 256 + kt * 32 + lc * 8);
            if (c0 + nt * 16 < 512) {   // q/k tile: swapped -> rows=channels
                acc[0][nt] = __builtin_amdgcn_mfma_f32_16x16x32_bf16(aw, bx0, acc[0][nt], 0, 0, 0);
                acc[1][nt] = __builtin_amdgcn_mfma_f32_16x16x32_bf16(aw, bx1, acc[1][nt], 0, 0, 0);
            } else {                    // v tile: original -> rows=i
                acc[0][nt] = __builtin_amdgcn_mfma_f32_16x16x32_bf16(bx0, aw, acc[0][nt], 0, 0, 0);
                acc[1][nt] = __builtin_amdgcn_mfma_f32_16x16x32_bf16(bx1, aw, acc[1][nt], 0, 0, 0);
            }
        }
    }
    #pragma unroll
    for (int ms = 0; ms < 2; ms++) {
        #pragma unroll
        for (int nt = 0; nt < 6; nt++) {
            int ct = c0 + nt * 16;
            if (ct < 512) {
                // lane holds channels ct+lc*4 .. +3 for row i = rbase+ms*16+lr
                int n0 = ct + lc * 4;
                int i  = rbase + ms * 16 + lr;
                if (mt >= 4 || i < 100) {
                    __bf16* dst = (n0 < 256) ? q : k;
                    int ch0 = n0 & 255;
                    int hh = ch0 >> 5, d0 = ch0 & 31;
                    bf16x4 pv;
                    #pragma unroll
                    for (int r = 0; r < 4; r++) pv[r] = (__bf16)acc[ms][nt][r];
                    *reinterpret_cast<bf16x4*>(&dst[(((size_t)b * 8 + hh) * 164 + i) * 32 + d0]) = pv;
                }
            } else {
                int ch = ct + lr - 512;
                int hh = ch >> 5, d = ch & 31;
                int i0 = rbase + ms * 16 + lc * 4;
                if (mt >= 4 || i0 < 100) {
                    bf16x4 pv;
                    #pragma unroll
                    for (int r = 0; r < 4; r++) pv[r] = (__bf16)acc[ms][nt][r];
                    *reinterpret_cast<bf16x4*>(&vt[((size_t)(b * 8 + hh) * 32 + d) * 176 + i0]) = pv;
                }
            }
        }
    }
}

// ---------------- fused attention v7 ----------------
// LDS pool 20352 elems (40704 B), 4 blocks/CU:
//   A  [0,7040)   Ks[176][40] (QK)  -> Vt[32][200] [0,6400) staged before MoE
//   B' [7040 + w*3328): per-wave chunk (reluS 16x136 | h1 16x72) -> P 16x200
//      (wave-local reuse: no barrier between MoE and softmax)
__global__ __launch_bounds__(256, 4) void attn_kernel(
    const __bf16* __restrict__ qg, const __bf16* __restrict__ kg,
    const __bf16* __restrict__ vtg, const float* __restrict__ gatesg,
    const unsigned* __restrict__ maskbg, const __bf16* __restrict__ w1t,
    const __bf16* __restrict__ w2t, __bf16* __restrict__ ohg)
{
    __shared__ __align__(16) __bf16 lds[20352];
    const int bh = blockIdx.x, rt = blockIdx.y, b = bh >> 3, tid = threadIdx.x;
    const int w = tid >> 6, l = tid & 63, lr = l & 15, lc = l >> 4;
    const int m0 = w * 16;
    const int WB  = 7040 + w * 3328;   // per-wave chunk (reluS / h1 / P)
    const int H1B = WB + 2176;

    // ---- stage K rows 0..175 (zeros >=164), stride 40 ----
    const __bf16* kbase = kg + (size_t)bh * 164 * 32;
    for (int c = tid; c < 704; c += 256) {
        int row = c >> 2, part = c & 3;
        bf16x8 val = (row < 164) ? ldb8(kbase + row * 32 + part * 8) : zero8();
        *reinterpret_cast<bf16x8*>(&lds[row * 40 + part * 8]) = val;
    }
    // ---- mask bits from packed words (uniform loads) ----
    const unsigned* mbp = maskbg + b * 6;
    unsigned mbits = 0;
    #pragma unroll
    for (int nt = 0; nt < 11; nt++)
        mbits |= ((mbp[nt >> 1] >> (((nt & 1) << 4) + lr)) & 1u) << nt;
    // hoisted Q-row load hides under K staging
    int qrow = rt * 64 + m0 + lr; if (qrow > 163) qrow = 163;
    bf16x8 afq = ldb8(qg + ((size_t)bh * 164 + qrow) * 32 + lc * 8);
    __syncthreads();

    // ---- QK^T -> raw scores in registers (11 tiles) ----
    f32x4 raw[11];
    __builtin_amdgcn_s_setprio(1);
    #pragma unroll
    for (int nt = 0; nt < 11; nt++) {
        bf16x8 bf = ldb8(&lds[(nt * 16 + lr) * 40 + lc * 8]);
        f32x4 acc = {0.f, 0.f, 0.f, 0.f};
        acc = __builtin_amdgcn_mfma_f32_16x16x32_bf16(afq, bf, acc, 0, 0, 0);
        bool bad = (mbits >> nt) & 1;
        #pragma unroll
        for (int r = 0; r < 4; r++)
            raw[nt][r] = bad ? -1e30f : acc[r] * 0.0625f;
    }
    __builtin_amdgcn_s_setprio(0);

    // write relu'd scores; col 100 = 1.0 (bias row for augmented GEMM1)
    if (rt < 2) {
        #pragma unroll
        for (int nt = 0; nt < 8; nt++) {
            int j = nt * 16 + lr;
            #pragma unroll
            for (int r = 0; r < 4; r++) {
                float v = raw[nt][r];
                v = (v < 0.f) ? 0.f : v;
                if (j >= 100) v = (j == 100) ? 1.f : 0.f;
                lds[WB + (lc * 4 + r) * 136 + j] = (__bf16)v;
            }
        }
    }
    __syncthreads();   // all Ks reads done -> region A free

    // ---- Vt stage into region A (latency hides under MoE compute) ----
    const __bf16* vtb = vtg + (size_t)bh * 32 * 176;
    #pragma unroll
    for (int p = 0; p < 3; p++) {
        int c = tid + p * 256;
        int row = c / 24, jc = c - row * 24, j0 = jc * 8;
        bf16x8 vv;
        if (j0 < 164) {
            vv = ldb8(vtb + row * 176 + j0);
            if (j0 == 160) { vv[4] = (__bf16)0.f; vv[5] = (__bf16)0.f; vv[6] = (__bf16)0.f; vv[7] = (__bf16)0.f; }
        } else vv = zero8();
        *reinterpret_cast<bf16x8*>(&lds[row * 200 + j0]) = vv;
    }

    // ---- MoE (biases folded into w1t/w2t; gates hoisted) ----
    if (rt < 2) {
        const int gi0 = rt * 64 + m0 + lc * 4;
        float4 gv[4];
        #pragma unroll
        for (int r = 0; r < 4; r++) {
            int gi = gi0 + r;
            gv[r] = (gi < 100)
                ? *reinterpret_cast<const float4*>(&gatesg[((size_t)bh * 100 + gi) * 4])
                : make_float4(0.f, 0.f, 0.f, 0.f);
        }
        for (int e = 0; e < 4; e++) {
            bf16x8 sa[4];
            #pragma unroll
            for (int kt = 0; kt < 4; kt++)
                sa[kt] = ldb8(&lds[WB + lr * 136 + kt * 32 + lc * 8]);
            #pragma unroll
            for (int nt = 0; nt < 4; nt++) {
                f32x4 acc = {0.f, 0.f, 0.f, 0.f};
                __builtin_amdgcn_s_setprio(1);
                #pragma unroll
                for (int kt = 0; kt < 4; kt++) {
                    bf16x8 bb = ldb8(w1t + (size_t)(e * 64 + nt * 16 + lr) * 128 + kt * 32 + lc * 8);
                    acc = __builtin_amdgcn_mfma_f32_16x16x32_bf16(sa[kt], bb, acc, 0, 0, 0);
                }
                __builtin_amdgcn_s_setprio(0);
                int n = nt * 16 + lr;
                #pragma unroll
                for (int r = 0; r < 4; r++) {
                    float v = acc[r];
                    if (v < 0.f) v = 0.f;
                    if (n == 50) v = 1.f;   // bias col for augmented GEMM2
                    lds[H1B + (lc * 4 + r) * 72 + n] = (__bf16)v;
                }
            }
            bf16x8 ha0 = ldb8(&lds[H1B + lr * 72 + lc * 8]);
            bf16x8 ha1 = ldb8(&lds[H1B + lr * 72 + 32 + lc * 8]);
            #pragma unroll
            for (int nt = 0; nt < 7; nt++) {
                f32x4 acc = {0.f, 0.f, 0.f, 0.f};
                __builtin_amdgcn_s_setprio(1);
                bf16x8 bb0 = ldb8(w2t + (size_t)(e * 112 + nt * 16 + lr) * 64 + lc * 8);
                acc = __builtin_amdgcn_mfma_f32_16x16x32_bf16(ha0, bb0, acc, 0, 0, 0);
                bf16x8 bb1 = ldb8(w2t + (size_t)(e * 112 + nt * 16 + lr) * 64 + 32 + lc * 8);
                acc = __builtin_amdgcn_mfma_f32_16x16x32_bf16(ha1, bb1, acc, 0, 0, 0);
                __builtin_amdgcn_s_setprio(0);
                #pragma unroll
                for (int r = 0; r < 4; r++) {
                    float v = acc[r];
                    if (v < 0.f) v = 0.f;
                    float ge = (e == 0) ? gv[r].x : (e == 1) ? gv[r].y
                             : (e == 2) ? gv[r].z : gv[r].w;
                    raw[nt][r] += v * ge;
                }
            }
        }
    }
    // NO barrier: P region is this wave's own chunk (overwrites own reluS/h1 only)

    // ---- in-register softmax; write probs P (stride 200, cols 176..191 zero) ----
    #pragma unroll
    for (int r = 0; r < 4; r++) {
        float m2 = raw[0][r];
        #pragma unroll
        for (int nt = 1; nt < 11; nt++) m2 = fmaxf(m2, raw[nt][r]);
        m2 = fmaxf(m2, __shfl_xor(m2, 1, 64));
        m2 = fmaxf(m2, __shfl_xor(m2, 2, 64));
        m2 = fmaxf(m2, __shfl_xor(m2, 4, 64));
        m2 = fmaxf(m2, __shfl_xor(m2, 8, 64));
        float s2 = 0.f;
        #pragma unroll
        for (int nt = 0; nt < 11; nt++) {
            float ev = __expf(raw[nt][r] - m2);
            raw[nt][r] = ev;
            s2 += ev;
        }
        s2 += __shfl_xor(s2, 1, 64);
        s2 += __shfl_xor(s2, 2, 64);
        s2 += __shfl_xor(s2, 4, 64);
        s2 += __shfl_xor(s2, 8, 64);
        float inv = (s2 > 0.f) ? 1.f / s2 : 0.f;
        #pragma unroll
        for (int nt = 0; nt < 11; nt++)
            lds[WB + (lc * 4 + r) * 200 + nt * 16 + lr] = (__bf16)(raw[nt][r] * inv);
        lds[WB + (lc * 4 + r) * 200 + 176 + lr] = (__bf16)0.f;
    }
    __syncthreads();   // Vt (cross-wave) fully staged; P is wave-local

    // ---- O^T = V^T @ P^T ----
    int gi = rt * 64 + m0 + lr;
    #pragma unroll
    for (int nt = 0; nt < 2; nt++) {
        f32x4 acc = {0.f, 0.f, 0.f, 0.f};
        __builtin_amdgcn_s_setprio(1);
        #pragma unroll
        for (int kt = 0; kt < 6; kt++) {
            bf16x8 va = ldb8(&lds[(nt * 16 + lr) * 200 + kt * 32 + lc * 8]);
            bf16x8 pb = ldb8(&lds[WB + lr * 200 + kt * 32 + lc * 8]);
            acc = __builtin_amdgcn_mfma_f32_16x16x32_bf16(va, pb, acc, 0, 0, 0);
        }
        __builtin_amdgcn_s_setprio(0);
        if (gi < 164) {
            bf16x4 ov;
            #pragma unroll
            for (int r = 0; r < 4; r++) ov[r] = (__bf16)acc[r];
            *reinterpret_cast<bf16x4*>(&ohg[((size_t)bh * 164 + gi) * 32 + nt * 16 + lc * 4]) = ov;
        }
    }
}

// ---------------- output projection (swapped operands, float4 stores) ----------------
__global__ __launch_bounds__(256) void outproj_kernel(
    const __bf16* __restrict__ oh, const __bf16* __restrict__ wot,
    const __bf16* __restrict__ wsm, float* __restrict__ out)
{
    __shared__ float bos[256];
    const int b = blockIdx.y;
    const int mt = blockIdx.x >> 2;
    const int ntile = blockIdx.x & 3;
    const int tid = threadIdx.x;
    bos[tid] = (float)wsm[740 + tid];
    __syncthreads();
    const int w = tid >> 6, l = tid & 63, lr = l & 15, lc = l >> 4;
    int row = mt * 64 + w * 16 + lr; if (row > 163) row = 163;
    f32x4 acc[4];
    #pragma unroll
    for (int nt = 0; nt < 4; nt++) acc[nt] = (f32x4){0.f, 0.f, 0.f, 0.f};
    #pragma unroll
    for (int kt = 0; kt < 8; kt++) {
        bf16x8 bo = ldb8(oh + (((size_t)b * 8 + kt) * 164 + row) * 32 + lc * 8);
        #pragma unroll
        for (int nt = 0; nt < 4; nt++) {
            bf16x8 aw = ldb8(wot + (size_t)(ntile * 64 + nt * 16 + lr) * 256 + kt * 32 + lc * 8);
            acc[nt] = __builtin_amdgcn_mfma_f32_16x16x32_bf16(aw, bo, acc[nt], 0, 0, 0);
        }
    }
    int i = mt * 64 + w * 16 + lr;
    if (i < 164) {
        #pragma unroll
        for (int nt = 0; nt < 4; nt++) {
            int n0 = ntile * 64 + nt * 16 + lc * 4;
            float4 st = make_float4(acc[nt][0] + bos[n0],
                                    acc[nt][1] + bos[n0 + 1],
                                    acc[nt][2] + bos[n0 + 2],
                                    acc[nt][3] + bos[n0 + 3]);
            *reinterpret_cast<float4*>(&out[((size_t)b * 164 + i) * 256 + n0]) = st;
        }
    }
}

extern "C" void kernel_launch(void* const* d_in, const int* in_sizes, int n_in,
                              void* d_out, int out_size, void* d_ws, size_t ws_size,
                              hipStream_t stream) {
    const void* x      = d_in[0];
    const void* mask   = d_in[1];
    const void* w_qk_s = d_in[2];
    const void* w_qk_q = d_in[3];
    const void* w_v    = d_in[4];
    const void* w_gate = d_in[5];
    const void* b_gate = d_in[6];
    const void* ln_g   = d_in[7];
    const void* ln_b   = d_in[8];
    const void* w1     = d_in[9];
    const void* b1     = d_in[10];
    const void* w2     = d_in[11];
    const void* b2     = d_in[12];
    const void* w_out  = d_in[13];
    const void* b_out  = d_in[14];
    float* out = (float*)d_out;

    char* ws = (char*)d_ws;
    size_t off = 0;
    auto nextp = [&](size_t bytes) {
        char* p = ws + off;
        off += (bytes + 255) & ~(size_t)255;
        return p;
    };
    const size_t QKV_ELEMS = (size_t)256 * 8 * 164 * 32;   // 10,747,904
    const size_t VT_ELEMS  = (size_t)256 * 8 * 32 * 176;   // 11,534,336
    int*      modes  = (int*)nextp(64);
    unsigned* maskb  = (unsigned*)nextp((size_t)256 * 6 * 4);
    __bf16* qws  = (__bf16*)nextp(QKV_ELEMS * 2);
    __bf16* kws  = (__bf16*)nextp(QKV_ELEMS * 2);
    __bf16* vtws = (__bf16*)nextp(VT_ELEMS * 2);
    __bf16* ohws = (__bf16*)nextp(QKV_ELEMS * 2);
    float*  gws  = (float*)nextp((size_t)2048 * 100 * 4 * 4);
    __bf16* Wts  = (__bf16*)nextp(768 * 256 * 2);
    __bf16* Wtq  = (__bf16*)nextp(768 * 256 * 2);
    __bf16* w1t  = (__bf16*)nextp(4 * 64 * 128 * 2);
    __bf16* w2t  = (__bf16*)nextp(4 * 112 * 64 * 2);
    __bf16* wot  = (__bf16*)nextp(256 * 256 * 2);
    __bf16* wsm  = (__bf16*)nextp(996 * 2);

    detect_kernel<<<64, 256, 0, stream>>>(x, mask, modes, maskb);
    prep_kernel<<<1268, 256, 0, stream>>>(w_qk_s, w_qk_q, w_v, w1, w2, w_out,
                                          w_gate, b_gate, ln_g, ln_b, b1, b2,
                                          b_out, modes, Wts, Wtq, w1t, w2t, wot, wsm);
    qkv_kernel<<<dim3(12, 256), 256, 0, stream>>>(x, Wts, Wtq, wsm, modes,
                                                  qws, kws, vtws, gws);
    attn_kernel<<<dim3(2048, 3), 256, 0, stream>>>(qws, kws, vtws, gws, maskb,
                                                   w1t, w2t, ohws);
    outproj_kernel<<<dim3(12, 256), 256, 0, stream>>>(ohws, wot, wsm, out);
}

// Round 4
// 513.757 us; speedup vs baseline: 1.1519x; 1.1519x over previous
//
#include <hip/hip_runtime.h>

typedef __bf16 bf16x8 __attribute__((ext_vector_type(8)));
typedef __bf16 bf16x4 __attribute__((ext_vector_type(4)));
typedef float  f32x4  __attribute__((ext_vector_type(4)));

__device__ __forceinline__ bf16x8 ldb8(const __bf16* p) {
    return *reinterpret_cast<const bf16x8*>(p);
}
__device__ __forceinline__ bf16x8 zero8() {
    bf16x8 z;
    #pragma unroll
    for (int i = 0; i < 8; i++) z[i] = (__bf16)0.f;
    return z;
}
// mode m: 0 = storage is bf16, 1 = storage is fp32
__device__ __forceinline__ __bf16 ldw(const void* p, int i, int m) {
    return m ? (__bf16)((const float*)p)[i] : ((const __bf16*)p)[i];
}
__device__ __forceinline__ bf16x8 ldx8(const void* p, size_t ei, int m) {
    if (m) {
        const float* f = (const float*)p + ei;
        f32x4 a = *reinterpret_cast<const f32x4*>(f);
        f32x4 b = *reinterpret_cast<const f32x4*>(f + 4);
        bf16x8 r;
        #pragma unroll
        for (int u = 0; u < 4; u++) { r[u] = (__bf16)a[u]; r[4 + u] = (__bf16)b[u]; }
        return r;
    }
    return ldb8((const __bf16*)p + ei);
}

// ---------------- detect: input dtype + packed mask bits (64 blocks) ----------------
// maskb: [256 b][6 u32] bitmask; bits >=164 pre-set (masked).
__global__ __launch_bounds__(256) void detect_kernel(
    const void* x, const void* mask, int* modes, unsigned* maskb)
{
    __shared__ int v32bad, v16bad, sbad;
    __shared__ unsigned mb[24];
    const int t = threadIdx.x, bid = blockIdx.x;
    if (t == 0) { v32bad = 0; v16bad = 0; sbad = 0; }
    if (t < 24) mb[t] = ((t % 6) == 5) ? 0xFFFFFFF0u : 0u;
    __syncthreads();
    const unsigned int* mw = (const unsigned int*)mask;
    int b32 = 0, b16 = 0;
    for (int i = t; i < 10496; i += 256) {
        unsigned int w = mw[i];
        if (!(w == 0u || w == 1u || w == 0x3F800000u)) b32++;
        unsigned int h0 = w & 0xFFFFu, h1 = w >> 16;
        if (!(h0 == 0u || h0 == 1u || h0 == 0x3F80u)) b16++;
        if (!(h1 == 0u || h1 == 1u || h1 == 0x3F80u)) b16++;
    }
    if (b32) atomicAdd(&v32bad, b32);
    if (b16) atomicAdd(&v16bad, b16);
    if (bid == 0) {
        const unsigned int* xw = (const unsigned int*)x;
        int bad = 0;
        for (int i = t; i < 2048; i += 256) {
            unsigned int w = xw[i];
            unsigned int el = (w >> 7) & 0xFF, eh = (w >> 23) & 0xFF;
            if (el >= 0x94 || el == 0xFF) bad++;
            if (eh >= 0x94 || eh == 0xFF) bad++;
        }
        if (bad) atomicAdd(&sbad, bad);
    }
    __syncthreads();
    const int mmode = (v32bad == 0) ? 0 : ((v16bad == 0) ? 2 : 1);
    if (bid == 0 && t == 0) { modes[0] = (sbad > 64) ? 1 : 0; modes[1] = mmode; }
    // this block owns batches bid*4 .. bid*4+3  (4*164 = 656 mask entries)
    const int lo = bid * 656;
    for (int i2 = t; i2 < 656; i2 += 256) {
        int i = lo + i2;
        int val;
        if (mmode == 0)      val = (((const int*)mask)[i] != 0);
        else if (mmode == 2) val = (((const unsigned short*)mask)[i] != 0);
        else                 val = (((const unsigned char*)mask)[i] != 0);
        if (val) {
            int ib = i2 / 164, jb = i2 - ib * 164;
            atomicOr(&mb[ib * 6 + (jb >> 5)], 1u << (jb & 31));
        }
    }
    __syncthreads();
    if (t < 24) maskb[bid * 24 + t] = mb[t];
}

// ---------------- prep: transpose/pad weights into ws (mode-aware) ----------------
// Bias fold: w1t[n][k==100] = b1[n]; w2t[n][k==50] = b2[n]  (augmented GEMM).
__global__ __launch_bounds__(256) void prep_kernel(
    const void* wqks, const void* wqkq, const void* wv, const void* w1,
    const void* w2, const void* wout, const void* wg, const void* bg,
    const void* lng, const void* lnb, const void* b1, const void* b2,
    const void* bout, const int* __restrict__ modes,
    __bf16* __restrict__ Wts, __bf16* __restrict__ Wtq,
    __bf16* __restrict__ w1t, __bf16* __restrict__ w2t,
    __bf16* __restrict__ wot, __bf16* __restrict__ wsm)
{
    const int m = modes[0];
    int i = blockIdx.x * 256 + threadIdx.x;
    if (i < 196608) {
        int n = i >> 8, k = i & 255;
        __bf16 vs, vq;
        if (n < 512) { vs = ldw(wqks, k * 512 + n, m); vq = ldw(wqkq, k * 512 + n, m); }
        else         { vs = ldw(wv, k * 256 + (n - 512), m); vq = vs; }
        Wts[i] = vs; Wtq[i] = vq;
        return;
    }
    i -= 196608;
    if (i < 32768) {
        int e = i >> 13, r = i & 8191, n = r >> 7, k = r & 127;
        __bf16 v = (__bf16)0.f;
        if (n < 50) {
            if (k < 100)       v = ldw(w1, (e * 100 + k) * 50 + n, m);
            else if (k == 100) v = ldw(b1, e * 50 + n, m);
        }
        w1t[i] = v;
        return;
    }
    i -= 32768;
    if (i < 28672) {
        int e = i / 7168, r = i % 7168, n = r >> 6, k = r & 63;
        __bf16 v = (__bf16)0.f;
        if (n < 100) {
            if (k < 50)       v = ldw(w2, (e * 50 + k) * 100 + n, m);
            else if (k == 50) v = ldw(b2, e * 100 + n, m);
        }
        w2t[i] = v;
        return;
    }
    i -= 28672;
    if (i < 65536) {
        int n = i >> 8, k = i & 255;
        wot[i] = ldw(wout, k * 256 + n, m);
        return;
    }
    i -= 65536;
    if (i < 996) {
        __bf16 v;
        if (i < 128)      v = ldw(wg, i, m);
        else if (i < 132) v = ldw(bg, i - 128, m);
        else if (i < 136) v = ldw(lng, i - 132, m);
        else if (i < 140) v = ldw(lnb, i - 136, m);
        else if (i < 340) v = ldw(b1, i - 140, m);
        else if (i < 740) v = ldw(b2, i - 340, m);
        else              v = ldw(bout, i - 740, m);
        wsm[i] = v;
    }
}

// ---------------- qkv projection GEMM + fused gate (round-2 proven form) ----------------
// grid (12, B): x = mt(0..5) * 2 + half(0..1).  Block = 32 rows x 384 cols.
// V is written TRANSPOSED: vt[bh][d(32)][i stride 176] (only i<164 written).
__global__ __launch_bounds__(256, 2) void qkv_kernel(
    const void* __restrict__ x, const __bf16* __restrict__ Wts,
    const __bf16* __restrict__ Wtq, const __bf16* __restrict__ wsm,
    const int* __restrict__ modes,
    __bf16* __restrict__ q, __bf16* __restrict__ k, __bf16* __restrict__ vt,
    float* __restrict__ gates)
{
    __shared__ __bf16 xs[32][264];
    __shared__ float wgf[128];
    __shared__ float gcst[12];
    const int m = modes[0];
    const int b = blockIdx.y;
    const int mt = blockIdx.x >> 1;
    const int half = blockIdx.x & 1;
    const __bf16* Wt = (mt < 4) ? Wts : Wtq;
    const int rbase = (mt < 4) ? mt * 32 : 100 + (mt - 4) * 32;
    const int tid = threadIdx.x;

    if (tid < 128) wgf[tid] = (float)wsm[tid];
    if (tid < 12)  gcst[tid] = (float)wsm[128 + tid];
    for (int c = tid; c < 1024; c += 256) {
        int row = c >> 5, part = c & 31;
        bf16x8 val = ldx8(x, ((size_t)b * 164 + rbase + row) * 256 + part * 8, m);
        *reinterpret_cast<bf16x8*>(&xs[row][part * 8]) = val;
    }
    __syncthreads();

    // ---- fused gate (only half==0 computes) ----
    if (half == 0) {
        int jg = rbase * 8 + tid;
        int h = jg / 164;
        int j = jg - h * 164;
        if (j < 100) {
            const __bf16* xp = &xs[tid >> 3][(tid & 7) * 32];
            float g[4] = {gcst[0], gcst[1], gcst[2], gcst[3]};
            #pragma unroll
            for (int p = 0; p < 4; p++) {
                bf16x8 xv = ldb8(xp + p * 8);
                #pragma unroll
                for (int u = 0; u < 8; u++) {
                    float f = (float)xv[u];
                    #pragma unroll
                    for (int e = 0; e < 4; e++) g[e] += f * wgf[(p * 8 + u) * 4 + e];
                }
            }
            float mu = 0.25f * (g[0] + g[1] + g[2] + g[3]);
            float var = 0.25f * ((g[0]-mu)*(g[0]-mu) + (g[1]-mu)*(g[1]-mu) +
                                 (g[2]-mu)*(g[2]-mu) + (g[3]-mu)*(g[3]-mu));
            float is = rsqrtf(var + 1e-5f);
            float mx = -3.0e38f;
            #pragma unroll
            for (int e = 0; e < 4; e++) {
                g[e] = (g[e] - mu) * is * gcst[4 + e] + gcst[8 + e];
                mx = fmaxf(mx, g[e]);
            }
            float s = 0.f;
            #pragma unroll
            for (int e = 0; e < 4; e++) { g[e] = __expf(g[e] - mx); s += g[e]; }
            float inv = 1.f / s;
            float4 gv = make_float4(g[0]*inv, g[1]*inv, g[2]*inv, g[3]*inv);
            *reinterpret_cast<float4*>(&gates[((size_t)(b * 8 + h) * 100 + j) * 4]) = gv;
        }
    }

    const int w = tid >> 6, l = tid & 63, lr = l & 15, lc = l >> 4;
    f32x4 acc[2][6];
    #pragma unroll
    for (int ms = 0; ms < 2; ms++)
        #pragma unroll
        for (int nt = 0; nt < 6; nt++) acc[ms][nt] = (f32x4){0.f, 0.f, 0.f, 0.f};

    #pragma unroll
    for (int kt = 0; kt < 8; kt++) {
        bf16x8 a0 = ldb8(&xs[lr][kt * 32 + lc * 8]);
        bf16x8 a1 = ldb8(&xs[16 + lr][kt * 32 + lc * 8]);
        #pragma unroll
        for (int nt = 0; nt < 6; nt++) {
            bf16x8 bb = ldb8(Wt + (size_t)(half * 384 + w * 96 + nt * 16 + lr) * 256 + kt * 32 + lc * 8);
            acc[0][nt] = __builtin_amdgcn_mfma_f32_16x16x32_bf16(a0, bb, acc[0][nt], 0, 0, 0);
            acc[1][nt] = __builtin_amdgcn_mfma_f32_16x16x32_bf16(a1, bb, acc[1][nt], 0, 0, 0);
        }
    }
    #pragma unroll
    for (int ms = 0; ms < 2; ms++) {
        #pragma unroll
        for (int nt = 0; nt < 6; nt++) {
            int c = half * 384 + w * 96 + nt * 16 + lr;
            int i0 = rbase + ms * 16 + lc * 4;
            if (c < 512) {
                __bf16* dst; int ch;
                if (c < 256) { dst = q; ch = c; }
                else         { dst = k; ch = c - 256; }
                int hh = ch >> 5, d = ch & 31;
                #pragma unroll
                for (int r = 0; r < 4; r++) {
                    int i = i0 + r;
                    if (mt >= 4 || i < 100)
                        dst[(((size_t)b * 8 + hh) * 164 + i) * 32 + d] = (__bf16)acc[ms][nt][r];
                }
            } else {
                int ch = c - 512, hh = ch >> 5, d = ch & 31;
                if (mt >= 4 || i0 < 100) {
                    bf16x4 pv;
                    #pragma unroll
                    for (int r = 0; r < 4; r++) pv[r] = (__bf16)acc[ms][nt][r];
                    *reinterpret_cast<bf16x4*>(&vt[((size_t)(b * 8 + hh) * 32 + d) * 176 + i0]) = pv;
                }
            }
        }
    }
}

// ---------------- fused attention v8 (round-2 structure + packed mask + bias fold) ----
// LDS pool 20352 elems (40704 B), 4 blocks/CU:
//   A  [0,7040)      Ks[176][40] (QK)  -> Vt[32][200] [0,6400) staged before MoE
//   B  [7040,15744)  reluS[64][136]    -> P [64][200] [7040,19840) after MoE
//   C1 [15744,20352) h1 [64][72] single buffer (wave-local rows, DS-pipe ordered)
__global__ __launch_bounds__(256, 4) void attn_kernel(
    const __bf16* __restrict__ qg, const __bf16* __restrict__ kg,
    const __bf16* __restrict__ vtg, const float* __restrict__ gatesg,
    const unsigned* __restrict__ maskbg, const __bf16* __restrict__ w1t,
    const __bf16* __restrict__ w2t, __bf16* __restrict__ ohg)
{
    __shared__ __align__(16) __bf16 lds[20352];
    const int RS_OFF = 7040;
    const int P_OFF  = 7040;
    const int H1_OFF = 15744;

    const int bh = blockIdx.x, rt = blockIdx.y, b = bh >> 3, tid = threadIdx.x;
    const int w = tid >> 6, l = tid & 63, lr = l & 15, lc = l >> 4;
    const int m0 = w * 16;

    // ---- stage K rows 0..175 (zeros >=164), stride 40 ----
    const __bf16* kbase = kg + (size_t)bh * 164 * 32;
    for (int c = tid; c < 704; c += 256) {
        int row = c >> 2, part = c & 3;
        bf16x8 val = (row < 164) ? ldb8(kbase + row * 32 + part * 8) : zero8();
        *reinterpret_cast<bf16x8*>(&lds[row * 40 + part * 8]) = val;
    }
    // ---- mask bits from packed words (uniform loads) ----
    const unsigned* mbp = maskbg + b * 6;
    unsigned mbits = 0;
    #pragma unroll
    for (int nt = 0; nt < 11; nt++)
        mbits |= ((mbp[nt >> 1] >> (((nt & 1) << 4) + lr)) & 1u) << nt;
    // hoisted Q-row load hides under K staging
    int qrow = rt * 64 + m0 + lr; if (qrow > 163) qrow = 163;
    bf16x8 afq = ldb8(qg + ((size_t)bh * 164 + qrow) * 32 + lc * 8);
    __syncthreads();

    // ---- QK^T -> raw scores in registers (11 tiles; tile 11 is all-masked) ----
    f32x4 raw[11];
    __builtin_amdgcn_s_setprio(1);
    #pragma unroll
    for (int nt = 0; nt < 11; nt++) {
        bf16x8 bf = ldb8(&lds[(nt * 16 + lr) * 40 + lc * 8]);
        f32x4 acc = {0.f, 0.f, 0.f, 0.f};
        acc = __builtin_amdgcn_mfma_f32_16x16x32_bf16(afq, bf, acc, 0, 0, 0);
        bool bad = (mbits >> nt) & 1;
        #pragma unroll
        for (int r = 0; r < 4; r++)
            raw[nt][r] = bad ? -1e30f : acc[r] * 0.0625f;
    }
    __builtin_amdgcn_s_setprio(0);

    // write relu'd scores; col 100 = 1.0 (bias row for augmented GEMM1)
    if (rt < 2) {
        #pragma unroll
        for (int nt = 0; nt < 8; nt++) {
            int j = nt * 16 + lr;
            #pragma unroll
            for (int r = 0; r < 4; r++) {
                float v = raw[nt][r];
                v = (v < 0.f) ? 0.f : v;
                if (j >= 100) v = (j == 100) ? 1.f : 0.f;
                lds[RS_OFF + (m0 + lc * 4 + r) * 136 + j] = (__bf16)v;
            }
        }
    }
    __syncthreads();   // all Ks reads done -> region A free

    // ---- Vt stage into region A (latency hides under MoE compute) ----
    const __bf16* vtb = vtg + (size_t)bh * 32 * 176;
    #pragma unroll
    for (int p = 0; p < 3; p++) {
        int c = tid + p * 256;
        int row = c / 24, jc = c - row * 24, j0 = jc * 8;
        bf16x8 vv;
        if (j0 < 164) {
            vv = ldb8(vtb + row * 176 + j0);
            if (j0 == 160) { vv[4] = (__bf16)0.f; vv[5] = (__bf16)0.f; vv[6] = (__bf16)0.f; vv[7] = (__bf16)0.f; }
        } else vv = zero8();
        *reinterpret_cast<bf16x8*>(&lds[row * 200 + j0]) = vv;
    }

    // ---- MoE (biases folded into w1t/w2t; per-expert gt loads; no held state) ----
    if (rt < 2) {
        const int gi0 = rt * 64 + m0 + lc * 4;
        for (int e = 0; e < 4; e++) {
            bf16x8 sa[4];
            #pragma unroll
            for (int kt = 0; kt < 4; kt++)
                sa[kt] = ldb8(&lds[RS_OFF + (m0 + lr) * 136 + kt * 32 + lc * 8]);
            #pragma unroll
            for (int nt = 0; nt < 4; nt++) {
                f32x4 acc = {0.f, 0.f, 0.f, 0.f};
                __builtin_amdgcn_s_setprio(1);
                #pragma unroll
                for (int kt = 0; kt < 4; kt++) {
                    bf16x8 bb = ldb8(w1t + (size_t)(e * 64 + nt * 16 + lr) * 128 + kt * 32 + lc * 8);
                    acc = __builtin_amdgcn_mfma_f32_16x16x32_bf16(sa[kt], bb, acc, 0, 0, 0);
                }
                __builtin_amdgcn_s_setprio(0);
                int n = nt * 16 + lr;
                #pragma unroll
                for (int r = 0; r < 4; r++) {
                    float v = acc[r];
                    if (v < 0.f) v = 0.f;
                    if (n == 50) v = 1.f;   // bias col for augmented GEMM2
                    lds[H1_OFF + (m0 + lc * 4 + r) * 72 + n] = (__bf16)v;
                }
            }
            bf16x8 ha0 = ldb8(&lds[H1_OFF + (m0 + lr) * 72 + lc * 8]);
            bf16x8 ha1 = ldb8(&lds[H1_OFF + (m0 + lr) * 72 + 32 + lc * 8]);
            float gt[4];
            #pragma unroll
            for (int r = 0; r < 4; r++) {
                int gi = gi0 + r;
                gt[r] = (gi < 100) ? gatesg[((size_t)bh * 100 + gi) * 4 + e] : 0.f;
            }
            #pragma unroll
            for (int nt = 0; nt < 7; nt++) {
                f32x4 acc = {0.f, 0.f, 0.f, 0.f};
                __builtin_amdgcn_s_setprio(1);
                bf16x8 bb0 = ldb8(w2t + (size_t)(e * 112 + nt * 16 + lr) * 64 + lc * 8);
                acc = __builtin_amdgcn_mfma_f32_16x16x32_bf16(ha0, bb0, acc, 0, 0, 0);
                bf16x8 bb1 = ldb8(w2t + (size_t)(e * 112 + nt * 16 + lr) * 64 + 32 + lc * 8);
                acc = __builtin_amdgcn_mfma_f32_16x16x32_bf16(ha1, bb1, acc, 0, 0, 0);
                __builtin_amdgcn_s_setprio(0);
                #pragma unroll
                for (int r = 0; r < 4; r++) {
                    float v = acc[r];
                    if (v < 0.f) v = 0.f;
                    raw[nt][r] += v * gt[r];
                }
            }
        }
    }
    __syncthreads();   // MoE reads of reluS/h1 done -> B/C1 reusable for P

    // ---- in-register softmax; write probs P (stride 200, cols 176..191 zero) ----
    #pragma unroll
    for (int r = 0; r < 4; r++) {
        float m2 = raw[0][r];
        #pragma unroll
        for (int nt = 1; nt < 11; nt++) m2 = fmaxf(m2, raw[nt][r]);
        m2 = fmaxf(m2, __shfl_xor(m2, 1, 64));
        m2 = fmaxf(m2, __shfl_xor(m2, 2, 64));
        m2 = fmaxf(m2, __shfl_xor(m2, 4, 64));
        m2 = fmaxf(m2, __shfl_xor(m2, 8, 64));
        float s2 = 0.f;
        #pragma unroll
        for (int nt = 0; nt < 11; nt++) {
            float ev = __expf(raw[nt][r] - m2);
            raw[nt][r] = ev;
            s2 += ev;
        }
        s2 += __shfl_xor(s2, 1, 64);
        s2 += __shfl_xor(s2, 2, 64);
        s2 += __shfl_xor(s2, 4, 64);
        s2 += __shfl_xor(s2, 8, 64);
        float inv = (s2 > 0.f) ? 1.f / s2 : 0.f;
        #pragma unroll
        for (int nt = 0; nt < 11; nt++)
            lds[P_OFF + (m0 + lc * 4 + r) * 200 + nt * 16 + lr] = (__bf16)(raw[nt][r] * inv);
        lds[P_OFF + (m0 + lc * 4 + r) * 200 + 176 + lr] = (__bf16)0.f;
    }
    __syncthreads();   // Vt + P fully staged

    // ---- O^T = V^T @ P^T ----
    int gi = rt * 64 + m0 + lr;
    #pragma unroll
    for (int nt = 0; nt < 2; nt++) {
        f32x4 acc = {0.f, 0.f, 0.f, 0.f};
        __builtin_amdgcn_s_setprio(1);
        #pragma unroll
        for (int kt = 0; kt < 6; kt++) {
            bf16x8 va = ldb8(&lds[(nt * 16 + lr) * 200 + kt * 32 + lc * 8]);
            bf16x8 pb = ldb8(&lds[P_OFF + (m0 + lr) * 200 + kt * 32 + lc * 8]);
            acc = __builtin_amdgcn_mfma_f32_16x16x32_bf16(va, pb, acc, 0, 0, 0);
        }
        __builtin_amdgcn_s_setprio(0);
        if (gi < 164) {
            bf16x4 ov;
            #pragma unroll
            for (int r = 0; r < 4; r++) ov[r] = (__bf16)acc[r];
            *reinterpret_cast<bf16x4*>(&ohg[((size_t)bh * 164 + gi) * 32 + nt * 16 + lc * 4]) = ov;
        }
    }
}

// ---------------- output projection (round-2 proven form, writes fp32) ----------------
__global__ __launch_bounds__(256) void outproj_kernel(
    const __bf16* __restrict__ oh, const __bf16* __restrict__ wot,
    const __bf16* __restrict__ wsm, float* __restrict__ out)
{
    const __bf16* bout = wsm + 740;
    const int b = blockIdx.y;
    const int mt = blockIdx.x >> 2;
    const int ntile = blockIdx.x & 3;
    const int tid = threadIdx.x;
    const int w = tid >> 6, l = tid & 63, lr = l & 15, lc = l >> 4;
    int row = mt * 64 + w * 16 + lr; if (row > 163) row = 163;
    f32x4 acc[4];
    #pragma unroll
    for (int nt = 0; nt < 4; nt++) acc[nt] = (f32x4){0.f, 0.f, 0.f, 0.f};
    #pragma unroll
    for (int kt = 0; kt < 8; kt++) {
        bf16x8 a = ldb8(oh + (((size_t)b * 8 + kt) * 164 + row) * 32 + lc * 8);
        #pragma unroll
        for (int nt = 0; nt < 4; nt++) {
            bf16x8 bb = ldb8(wot + (size_t)(ntile * 64 + nt * 16 + lr) * 256 + kt * 32 + lc * 8);
            acc[nt] = __builtin_amdgcn_mfma_f32_16x16x32_bf16(a, bb, acc[nt], 0, 0, 0);
        }
    }
    #pragma unroll
    for (int nt = 0; nt < 4; nt++) {
        int n = ntile * 64 + nt * 16 + lr;
        float bias = (float)bout[n];
        #pragma unroll
        for (int r = 0; r < 4; r++) {
            int i = mt * 64 + w * 16 + lc * 4 + r;
            if (i < 164)
                out[((size_t)b * 164 + i) * 256 + n] = acc[nt][r] + bias;
        }
    }
}

extern "C" void kernel_launch(void* const* d_in, const int* in_sizes, int n_in,
                              void* d_out, int out_size, void* d_ws, size_t ws_size,
                              hipStream_t stream) {
    const void* x      = d_in[0];
    const void* mask   = d_in[1];
    const void* w_qk_s = d_in[2];
    const void* w_qk_q = d_in[3];
    const void* w_v    = d_in[4];
    const void* w_gate = d_in[5];
    const void* b_gate = d_in[6];
    const void* ln_g   = d_in[7];
    const void* ln_b   = d_in[8];
    const void* w1     = d_in[9];
    const void* b1     = d_in[10];
    const void* w2     = d_in[11];
    const void* b2     = d_in[12];
    const void* w_out  = d_in[13];
    const void* b_out  = d_in[14];
    float* out = (float*)d_out;

    char* ws = (char*)d_ws;
    size_t off = 0;
    auto nextp = [&](size_t bytes) {
        char* p = ws + off;
        off += (bytes + 255) & ~(size_t)255;
        return p;
    };
    const size_t QKV_ELEMS = (size_t)256 * 8 * 164 * 32;   // 10,747,904
    const size_t VT_ELEMS  = (size_t)256 * 8 * 32 * 176;   // 11,534,336
    int*      modes  = (int*)nextp(64);
    unsigned* maskb  = (unsigned*)nextp((size_t)256 * 6 * 4);
    __bf16* qws  = (__bf16*)nextp(QKV_ELEMS * 2);
    __bf16* kws  = (__bf16*)nextp(QKV_ELEMS * 2);
    __bf16* vtws = (__bf16*)nextp(VT_ELEMS * 2);
    __bf16* ohws = (__bf16*)nextp(QKV_ELEMS * 2);
    float*  gws  = (float*)nextp((size_t)2048 * 100 * 4 * 4);
    __bf16* Wts  = (__bf16*)nextp(768 * 256 * 2);
    __bf16* Wtq  = (__bf16*)nextp(768 * 256 * 2);
    __bf16* w1t  = (__bf16*)nextp(4 * 64 * 128 * 2);
    __bf16* w2t  = (__bf16*)nextp(4 * 112 * 64 * 2);
    __bf16* wot  = (__bf16*)nextp(256 * 256 * 2);
    __bf16* wsm  = (__bf16*)nextp(996 * 2);

    detect_kernel<<<64, 256, 0, stream>>>(x, mask, modes, maskb);
    prep_kernel<<<1268, 256, 0, stream>>>(w_qk_s, w_qk_q, w_v, w1, w2, w_out,
                                          w_gate, b_gate, ln_g, ln_b, b1, b2,
                                          b_out, modes, Wts, Wtq, w1t, w2t, wot, wsm);
    qkv_kernel<<<dim3(12, 256), 256, 0, stream>>>(x, Wts, Wtq, wsm, modes,
                                                  qws, kws, vtws, gws);
    attn_kernel<<<dim3(2048, 3), 256, 0, stream>>>(qws, kws, vtws, gws, maskb,
                                                   w1t, w2t, ohws);
    outproj_kernel<<<dim3(12, 256), 256, 0, stream>>>(ohws, wot, wsm, out);
}

// Round 5
// 490.398 us; speedup vs baseline: 1.2067x; 1.0476x over previous
//
#include <hip/hip_runtime.h>

typedef __bf16 bf16x8 __attribute__((ext_vector_type(8)));
typedef __bf16 bf16x4 __attribute__((ext_vector_type(4)));
typedef float  f32x4  __attribute__((ext_vector_type(4)));

__device__ __forceinline__ bf16x8 ldb8(const __bf16* p) {
    return *reinterpret_cast<const bf16x8*>(p);
}
__device__ __forceinline__ bf16x8 zero8() {
    bf16x8 z;
    #pragma unroll
    for (int i = 0; i < 8; i++) z[i] = (__bf16)0.f;
    return z;
}
// mode m: 0 = storage is bf16, 1 = storage is fp32
__device__ __forceinline__ __bf16 ldw(const void* p, int i, int m) {
    return m ? (__bf16)((const float*)p)[i] : ((const __bf16*)p)[i];
}
__device__ __forceinline__ bf16x8 ldx8(const void* p, size_t ei, int m) {
    if (m) {
        const float* f = (const float*)p + ei;
        f32x4 a = *reinterpret_cast<const f32x4*>(f);
        f32x4 b = *reinterpret_cast<const f32x4*>(f + 4);
        bf16x8 r;
        #pragma unroll
        for (int u = 0; u < 4; u++) { r[u] = (__bf16)a[u]; r[4 + u] = (__bf16)b[u]; }
        return r;
    }
    return ldb8((const __bf16*)p + ei);
}

// ---------------- prep: self-detect dtype + weights + mask bits ----------------
// grid 1332: blocks 0..1267 weight transpose/pad, blocks 1268..1331 maskb build.
// Bias fold: w1t[n][k==100] = b1[n]; w2t[n][k==50] = b2[n]  (augmented GEMM).
// maskb: [256 b][6 u32] bitmask; bits >=164 pre-set (masked).
__global__ __launch_bounds__(256) void prep_kernel(
    const void* x, const void* mask,
    const void* wqks, const void* wqkq, const void* wv, const void* w1,
    const void* w2, const void* wout, const void* wg, const void* bg,
    const void* lng, const void* lnb, const void* b1, const void* b2,
    const void* bout, int* modes, unsigned* maskb,
    __bf16* __restrict__ Wts, __bf16* __restrict__ Wtq,
    __bf16* __restrict__ w1t, __bf16* __restrict__ w2t,
    __bf16* __restrict__ wot, __bf16* __restrict__ wsm)
{
    __shared__ int sbad;
    const int t = threadIdx.x, bid = blockIdx.x;
    if (t == 0) sbad = 0;
    __syncthreads();
    // every block self-detects x dtype (8 KB scan, L2-hit)
    {
        const unsigned int* xw = (const unsigned int*)x;
        int bad = 0;
        for (int i = t; i < 2048; i += 256) {
            unsigned int w = xw[i];
            unsigned int el = (w >> 7) & 0xFF, eh = (w >> 23) & 0xFF;
            if (el >= 0x94 || el == 0xFF) bad++;
            if (eh >= 0x94 || eh == 0xFF) bad++;
        }
        if (bad) atomicAdd(&sbad, bad);
    }
    __syncthreads();
    const int m = (sbad > 64) ? 1 : 0;

    if (bid >= 1268) {
        // ---- mask blocks: detect mask width locally, build packed bits ----
        __shared__ int v32bad, v16bad;
        __shared__ unsigned mb[24];
        const int mbid = bid - 1268;                 // 0..63
        if (t == 0) { v32bad = 0; v16bad = 0; }
        if (t < 24) mb[t] = ((t % 6) == 5) ? 0xFFFFFFF0u : 0u;
        __syncthreads();
        const unsigned int* mw = (const unsigned int*)mask;
        int b32 = 0, b16 = 0;
        for (int i = t; i < 10496; i += 256) {
            unsigned int w = mw[i];
            if (!(w == 0u || w == 1u || w == 0x3F800000u)) b32++;
            unsigned int h0 = w & 0xFFFFu, h1 = w >> 16;
            if (!(h0 == 0u || h0 == 1u || h0 == 0x3F80u)) b16++;
            if (!(h1 == 0u || h1 == 1u || h1 == 0x3F80u)) b16++;
        }
        if (b32) atomicAdd(&v32bad, b32);
        if (b16) atomicAdd(&v16bad, b16);
        __syncthreads();
        const int mmode = (v32bad == 0) ? 0 : ((v16bad == 0) ? 2 : 1);
        if (mbid == 0 && t == 0) { modes[0] = m; modes[1] = mmode; }
        const int lo = mbid * 656;                   // 4 batches per block
        for (int i2 = t; i2 < 656; i2 += 256) {
            int i = lo + i2;
            int val;
            if (mmode == 0)      val = (((const int*)mask)[i] != 0);
            else if (mmode == 2) val = (((const unsigned short*)mask)[i] != 0);
            else                 val = (((const unsigned char*)mask)[i] != 0);
            if (val) {
                int ib = i2 / 164, jb = i2 - ib * 164;
                atomicOr(&mb[ib * 6 + (jb >> 5)], 1u << (jb & 31));
            }
        }
        __syncthreads();
        if (t < 24) maskb[mbid * 24 + t] = mb[t];
        return;
    }

    int i = bid * 256 + t;
    if (i < 196608) {
        int n = i >> 8, k = i & 255;
        __bf16 vs, vq;
        if (n < 512) { vs = ldw(wqks, k * 512 + n, m); vq = ldw(wqkq, k * 512 + n, m); }
        else         { vs = ldw(wv, k * 256 + (n - 512), m); vq = vs; }
        Wts[i] = vs; Wtq[i] = vq;
        return;
    }
    i -= 196608;
    if (i < 32768) {
        int e = i >> 13, r = i & 8191, n = r >> 7, k = r & 127;
        __bf16 v = (__bf16)0.f;
        if (n < 50) {
            if (k < 100)       v = ldw(w1, (e * 100 + k) * 50 + n, m);
            else if (k == 100) v = ldw(b1, e * 50 + n, m);
        }
        w1t[i] = v;
        return;
    }
    i -= 32768;
    if (i < 28672) {
        int e = i / 7168, r = i % 7168, n = r >> 6, k = r & 63;
        __bf16 v = (__bf16)0.f;
        if (n < 100) {
            if (k < 50)       v = ldw(w2, (e * 50 + k) * 100 + n, m);
            else if (k == 50) v = ldw(b2, e * 100 + n, m);
        }
        w2t[i] = v;
        return;
    }
    i -= 28672;
    if (i < 65536) {
        int n = i >> 8, k = i & 255;
        wot[i] = ldw(wout, k * 256 + n, m);
        return;
    }
    i -= 65536;
    if (i < 996) {
        __bf16 v;
        if (i < 128)      v = ldw(wg, i, m);
        else if (i < 132) v = ldw(bg, i - 128, m);
        else if (i < 136) v = ldw(lng, i - 132, m);
        else if (i < 140) v = ldw(lnb, i - 136, m);
        else if (i < 340) v = ldw(b1, i - 140, m);
        else if (i < 740) v = ldw(b2, i - 340, m);
        else              v = ldw(bout, i - 740, m);
        wsm[i] = v;
    }
}

// ---------------- qkv projection GEMM + fused gate (round-2 proven form) ----------------
// grid (12, B): x = mt(0..5) * 2 + half(0..1).  Block = 32 rows x 384 cols.
// V is written TRANSPOSED: vt[bh][d(32)][i stride 176] (only i<164 written).
__global__ __launch_bounds__(256, 2) void qkv_kernel(
    const void* __restrict__ x, const __bf16* __restrict__ Wts,
    const __bf16* __restrict__ Wtq, const __bf16* __restrict__ wsm,
    const int* __restrict__ modes,
    __bf16* __restrict__ q, __bf16* __restrict__ k, __bf16* __restrict__ vt,
    float* __restrict__ gates)
{
    __shared__ __bf16 xs[32][264];
    __shared__ float wgf[128];
    __shared__ float gcst[12];
    const int m = modes[0];
    const int b = blockIdx.y;
    const int mt = blockIdx.x >> 1;
    const int half = blockIdx.x & 1;
    const __bf16* Wt = (mt < 4) ? Wts : Wtq;
    const int rbase = (mt < 4) ? mt * 32 : 100 + (mt - 4) * 32;
    const int tid = threadIdx.x;

    if (tid < 128) wgf[tid] = (float)wsm[tid];
    if (tid < 12)  gcst[tid] = (float)wsm[128 + tid];
    for (int c = tid; c < 1024; c += 256) {
        int row = c >> 5, part = c & 31;
        bf16x8 val = ldx8(x, ((size_t)b * 164 + rbase + row) * 256 + part * 8, m);
        *reinterpret_cast<bf16x8*>(&xs[row][part * 8]) = val;
    }
    __syncthreads();

    // ---- fused gate (only half==0 computes) ----
    if (half == 0) {
        int jg = rbase * 8 + tid;
        int h = jg / 164;
        int j = jg - h * 164;
        if (j < 100) {
            const __bf16* xp = &xs[tid >> 3][(tid & 7) * 32];
            float g[4] = {gcst[0], gcst[1], gcst[2], gcst[3]};
            #pragma unroll
            for (int p = 0; p < 4; p++) {
                bf16x8 xv = ldb8(xp + p * 8);
                #pragma unroll
                for (int u = 0; u < 8; u++) {
                    float f = (float)xv[u];
                    #pragma unroll
                    for (int e = 0; e < 4; e++) g[e] += f * wgf[(p * 8 + u) * 4 + e];
                }
            }
            float mu = 0.25f * (g[0] + g[1] + g[2] + g[3]);
            float var = 0.25f * ((g[0]-mu)*(g[0]-mu) + (g[1]-mu)*(g[1]-mu) +
                                 (g[2]-mu)*(g[2]-mu) + (g[3]-mu)*(g[3]-mu));
            float is = rsqrtf(var + 1e-5f);
            float mx = -3.0e38f;
            #pragma unroll
            for (int e = 0; e < 4; e++) {
                g[e] = (g[e] - mu) * is * gcst[4 + e] + gcst[8 + e];
                mx = fmaxf(mx, g[e]);
            }
            float s = 0.f;
            #pragma unroll
            for (int e = 0; e < 4; e++) { g[e] = __expf(g[e] - mx); s += g[e]; }
            float inv = 1.f / s;
            float4 gv = make_float4(g[0]*inv, g[1]*inv, g[2]*inv, g[3]*inv);
            *reinterpret_cast<float4*>(&gates[((size_t)(b * 8 + h) * 100 + j) * 4]) = gv;
        }
    }

    const int w = tid >> 6, l = tid & 63, lr = l & 15, lc = l >> 4;
    f32x4 acc[2][6];
    #pragma unroll
    for (int ms = 0; ms < 2; ms++)
        #pragma unroll
        for (int nt = 0; nt < 6; nt++) acc[ms][nt] = (f32x4){0.f, 0.f, 0.f, 0.f};

    #pragma unroll
    for (int kt = 0; kt < 8; kt++) {
        bf16x8 a0 = ldb8(&xs[lr][kt * 32 + lc * 8]);
        bf16x8 a1 = ldb8(&xs[16 + lr][kt * 32 + lc * 8]);
        #pragma unroll
        for (int nt = 0; nt < 6; nt++) {
            bf16x8 bb = ldb8(Wt + (size_t)(half * 384 + w * 96 + nt * 16 + lr) * 256 + kt * 32 + lc * 8);
            acc[0][nt] = __builtin_amdgcn_mfma_f32_16x16x32_bf16(a0, bb, acc[0][nt], 0, 0, 0);
            acc[1][nt] = __builtin_amdgcn_mfma_f32_16x16x32_bf16(a1, bb, acc[1][nt], 0, 0, 0);
        }
    }
    #pragma unroll
    for (int ms = 0; ms < 2; ms++) {
        #pragma unroll
        for (int nt = 0; nt < 6; nt++) {
            int c = half * 384 + w * 96 + nt * 16 + lr;
            int i0 = rbase + ms * 16 + lc * 4;
            if (c < 512) {
                __bf16* dst; int ch;
                if (c < 256) { dst = q; ch = c; }
                else         { dst = k; ch = c - 256; }
                int hh = ch >> 5, d = ch & 31;
                #pragma unroll
                for (int r = 0; r < 4; r++) {
                    int i = i0 + r;
                    if (mt >= 4 || i < 100)
                        dst[(((size_t)b * 8 + hh) * 164 + i) * 32 + d] = (__bf16)acc[ms][nt][r];
                }
            } else {
                int ch = c - 512, hh = ch >> 5, d = ch & 31;
                if (mt >= 4 || i0 < 100) {
                    bf16x4 pv;
                    #pragma unroll
                    for (int r = 0; r < 4; r++) pv[r] = (__bf16)acc[ms][nt][r];
                    *reinterpret_cast<bf16x4*>(&vt[((size_t)(b * 8 + hh) * 32 + d) * 176 + i0]) = pv;
                }
            }
        }
    }
}

// ---------------- fused attention v9: XCD-swizzled flat grid + MoE wave skip ----
// flat grid 6144: xcd = flat&7, j = flat>>3, bh = ((j&255)<<3)|xcd, rt = j>>8
// -> all 3 rt blocks of a bh land on the SAME XCD (K/Vt L2 reuse); rt=0 first.
// LDS pool 20352 elems (40704 B), 4 blocks/CU:
//   A  [0,7040)      Ks[176][40] (QK)  -> Vt[32][200] [0,6400) staged before MoE
//   B  [7040,15744)  reluS[64][136]    -> P [64][200] [7040,19840) after MoE
//   C1 [15744,20352) h1 [64][72] single buffer (wave-local rows, DS-pipe ordered)
__global__ __launch_bounds__(256, 4) void attn_kernel(
    const __bf16* __restrict__ qg, const __bf16* __restrict__ kg,
    const __bf16* __restrict__ vtg, const float* __restrict__ gatesg,
    const unsigned* __restrict__ maskbg, const __bf16* __restrict__ w1t,
    const __bf16* __restrict__ w2t, __bf16* __restrict__ ohg)
{
    __shared__ __align__(16) __bf16 lds[20352];
    const int RS_OFF = 7040;
    const int P_OFF  = 7040;
    const int H1_OFF = 15744;

    const int flat = blockIdx.x;
    const int xcd = flat & 7, j5 = flat >> 3;
    const int bh = ((j5 & 255) << 3) | xcd;
    const int rt = j5 >> 8;
    const int b = bh >> 3, tid = threadIdx.x;
    const int w = tid >> 6, l = tid & 63, lr = l & 15, lc = l >> 4;
    const int m0 = w * 16;
    const bool moe_wave = (rt * 64 + m0) < 100;   // wave-level MoE participation

    // ---- stage K rows 0..163 (rows 164..175 garbage; tile 10 is mask-protected) ----
    const __bf16* kbase = kg + (size_t)bh * 164 * 32;
    for (int c = tid; c < 656; c += 256) {
        int row = c >> 2, part = c & 3;
        bf16x8 val = ldb8(kbase + row * 32 + part * 8);
        *reinterpret_cast<bf16x8*>(&lds[row * 40 + part * 8]) = val;
    }
    // ---- mask bits from packed words (uniform loads) ----
    const unsigned* mbp = maskbg + b * 6;
    unsigned mbits = 0;
    #pragma unroll
    for (int nt = 0; nt < 11; nt++)
        mbits |= ((mbp[nt >> 1] >> (((nt & 1) << 4) + lr)) & 1u) << nt;
    // hoisted Q-row load hides under K staging
    int qrow = rt * 64 + m0 + lr; if (qrow > 163) qrow = 163;
    bf16x8 afq = ldb8(qg + ((size_t)bh * 164 + qrow) * 32 + lc * 8);
    __syncthreads();

    // ---- QK^T -> raw scores in registers (11 tiles; tile 11 is all-masked) ----
    f32x4 raw[11];
    __builtin_amdgcn_s_setprio(1);
    #pragma unroll
    for (int nt = 0; nt < 11; nt++) {
        bf16x8 bf = ldb8(&lds[(nt * 16 + lr) * 40 + lc * 8]);
        f32x4 acc = {0.f, 0.f, 0.f, 0.f};
        acc = __builtin_amdgcn_mfma_f32_16x16x32_bf16(afq, bf, acc, 0, 0, 0);
        bool bad = (mbits >> nt) & 1;
        #pragma unroll
        for (int r = 0; r < 4; r++)
            raw[nt][r] = bad ? -1e30f : acc[r] * 0.0625f;
    }
    __builtin_amdgcn_s_setprio(0);

    // write relu'd scores; col 100 = 1.0 (bias row for augmented GEMM1)
    if (moe_wave) {
        #pragma unroll
        for (int nt = 0; nt < 8; nt++) {
            int j = nt * 16 + lr;
            #pragma unroll
            for (int r = 0; r < 4; r++) {
                float v = raw[nt][r];
                v = (v < 0.f) ? 0.f : v;
                if (j >= 100) v = (j == 100) ? 1.f : 0.f;
                lds[RS_OFF + (m0 + lc * 4 + r) * 136 + j] = (__bf16)v;
            }
        }
    }
    __syncthreads();   // all Ks reads done -> region A free

    // ---- Vt stage into region A (latency hides under MoE compute) ----
    const __bf16* vtb = vtg + (size_t)bh * 32 * 176;
    #pragma unroll
    for (int p = 0; p < 3; p++) {
        int c = tid + p * 256;
        int row = c / 24, jc = c - row * 24, j0 = jc * 8;
        bf16x8 vv;
        if (j0 < 164) {
            vv = ldb8(vtb + row * 176 + j0);
            if (j0 == 160) { vv[4] = (__bf16)0.f; vv[5] = (__bf16)0.f; vv[6] = (__bf16)0.f; vv[7] = (__bf16)0.f; }
        } else vv = zero8();
        *reinterpret_cast<bf16x8*>(&lds[row * 200 + j0]) = vv;
    }

    // ---- MoE (biases folded into w1t/w2t; per-expert gt loads; no held state) ----
    if (moe_wave) {
        const int gi0 = rt * 64 + m0 + lc * 4;
        for (int e = 0; e < 4; e++) {
            bf16x8 sa[4];
            #pragma unroll
            for (int kt = 0; kt < 4; kt++)
                sa[kt] = ldb8(&lds[RS_OFF + (m0 + lr) * 136 + kt * 32 + lc * 8]);
            #pragma unroll
            for (int nt = 0; nt < 4; nt++) {
                f32x4 acc = {0.f, 0.f, 0.f, 0.f};
                __builtin_amdgcn_s_setprio(1);
                #pragma unroll
                for (int kt = 0; kt < 4; kt++) {
                    bf16x8 bb = ldb8(w1t + (size_t)(e * 64 + nt * 16 + lr) * 128 + kt * 32 + lc * 8);
                    acc = __builtin_amdgcn_mfma_f32_16x16x32_bf16(sa[kt], bb, acc, 0, 0, 0);
                }
                __builtin_amdgcn_s_setprio(0);
                int n = nt * 16 + lr;
                #pragma unroll
                for (int r = 0; r < 4; r++) {
                    float v = acc[r];
                    if (v < 0.f) v = 0.f;
                    if (n == 50) v = 1.f;   // bias col for augmented GEMM2
                    lds[H1_OFF + (m0 + lc * 4 + r) * 72 + n] = (__bf16)v;
                }
            }
            bf16x8 ha0 = ldb8(&lds[H1_OFF + (m0 + lr) * 72 + lc * 8]);
            bf16x8 ha1 = ldb8(&lds[H1_OFF + (m0 + lr) * 72 + 32 + lc * 8]);
            float gt[4];
            #pragma unroll
            for (int r = 0; r < 4; r++) {
                int gi = gi0 + r;
                gt[r] = (gi < 100) ? gatesg[((size_t)bh * 100 + gi) * 4 + e] : 0.f;
            }
            #pragma unroll
            for (int nt = 0; nt < 7; nt++) {
                f32x4 acc = {0.f, 0.f, 0.f, 0.f};
                __builtin_amdgcn_s_setprio(1);
                bf16x8 bb0 = ldb8(w2t + (size_t)(e * 112 + nt * 16 + lr) * 64 + lc * 8);
                acc = __builtin_amdgcn_mfma_f32_16x16x32_bf16(ha0, bb0, acc, 0, 0, 0);
                bf16x8 bb1 = ldb8(w2t + (size_t)(e * 112 + nt * 16 + lr) * 64 + 32 + lc * 8);
                acc = __builtin_amdgcn_mfma_f32_16x16x32_bf16(ha1, bb1, acc, 0, 0, 0);
                __builtin_amdgcn_s_setprio(0);
                #pragma unroll
                for (int r = 0; r < 4; r++) {
                    float v = acc[r];
                    if (v < 0.f) v = 0.f;
                    raw[nt][r] += v * gt[r];
                }
            }
        }
    }
    __syncthreads();   // MoE reads of reluS/h1 done -> B/C1 reusable for P

    // ---- in-register softmax; write probs P (stride 200, cols 176..191 zero) ----
    #pragma unroll
    for (int r = 0; r < 4; r++) {
        float m2 = raw[0][r];
        #pragma unroll
        for (int nt = 1; nt < 11; nt++) m2 = fmaxf(m2, raw[nt][r]);
        m2 = fmaxf(m2, __shfl_xor(m2, 1, 64));
        m2 = fmaxf(m2, __shfl_xor(m2, 2, 64));
        m2 = fmaxf(m2, __shfl_xor(m2, 4, 64));
        m2 = fmaxf(m2, __shfl_xor(m2, 8, 64));
        float s2 = 0.f;
        #pragma unroll
        for (int nt = 0; nt < 11; nt++) {
            float ev = __expf(raw[nt][r] - m2);
            raw[nt][r] = ev;
            s2 += ev;
        }
        s2 += __shfl_xor(s2, 1, 64);
        s2 += __shfl_xor(s2, 2, 64);
        s2 += __shfl_xor(s2, 4, 64);
        s2 += __shfl_xor(s2, 8, 64);
        float inv = (s2 > 0.f) ? 1.f / s2 : 0.f;
        #pragma unroll
        for (int nt = 0; nt < 11; nt++)
            lds[P_OFF + (m0 + lc * 4 + r) * 200 + nt * 16 + lr] = (__bf16)(raw[nt][r] * inv);
        lds[P_OFF + (m0 + lc * 4 + r) * 200 + 176 + lr] = (__bf16)0.f;
    }
    __syncthreads();   // Vt + P fully staged

    // ---- O^T = V^T @ P^T ----
    int gi = rt * 64 + m0 + lr;
    #pragma unroll
    for (int nt = 0; nt < 2; nt++) {
        f32x4 acc = {0.f, 0.f, 0.f, 0.f};
        __builtin_amdgcn_s_setprio(1);
        #pragma unroll
        for (int kt = 0; kt < 6; kt++) {
            bf16x8 va = ldb8(&lds[(nt * 16 + lr) * 200 + kt * 32 + lc * 8]);
            bf16x8 pb = ldb8(&lds[P_OFF + (m0 + lr) * 200 + kt * 32 + lc * 8]);
            acc = __builtin_amdgcn_mfma_f32_16x16x32_bf16(va, pb, acc, 0, 0, 0);
        }
        __builtin_amdgcn_s_setprio(0);
        if (gi < 164) {
            bf16x4 ov;
            #pragma unroll
            for (int r = 0; r < 4; r++) ov[r] = (__bf16)acc[r];
            *reinterpret_cast<bf16x4*>(&ohg[((size_t)bh * 164 + gi) * 32 + nt * 16 + lc * 4]) = ov;
        }
    }
}

// ---------------- output projection (round-2 proven form, writes fp32) ----------------
__global__ __launch_bounds__(256) void outproj_kernel(
    const __bf16* __restrict__ oh, const __bf16* __restrict__ wot,
    const __bf16* __restrict__ wsm, float* __restrict__ out)
{
    const __bf16* bout = wsm + 740;
    const int b = blockIdx.y;
    const int mt = blockIdx.x >> 2;
    const int ntile = blockIdx.x & 3;
    const int tid = threadIdx.x;
    const int w = tid >> 6, l = tid & 63, lr = l & 15, lc = l >> 4;
    int row = mt * 64 + w * 16 + lr; if (row > 163) row = 163;
    f32x4 acc[4];
    #pragma unroll
    for (int nt = 0; nt < 4; nt++) acc[nt] = (f32x4){0.f, 0.f, 0.f, 0.f};
    #pragma unroll
    for (int kt = 0; kt < 8; kt++) {
        bf16x8 a = ldb8(oh + (((size_t)b * 8 + kt) * 164 + row) * 32 + lc * 8);
        #pragma unroll
        for (int nt = 0; nt < 4; nt++) {
            bf16x8 bb = ldb8(wot + (size_t)(ntile * 64 + nt * 16 + lr) * 256 + kt * 32 + lc * 8);
            acc[nt] = __builtin_amdgcn_mfma_f32_16x16x32_bf16(a, bb, acc[nt], 0, 0, 0);
        }
    }
    #pragma unroll
    for (int nt = 0; nt < 4; nt++) {
        int n = ntile * 64 + nt * 16 + lr;
        float bias = (float)bout[n];
        #pragma unroll
        for (int r = 0; r < 4; r++) {
            int i = mt * 64 + w * 16 + lc * 4 + r;
            if (i < 164)
                out[((size_t)b * 164 + i) * 256 + n] = acc[nt][r] + bias;
        }
    }
}

extern "C" void kernel_launch(void* const* d_in, const int* in_sizes, int n_in,
                              void* d_out, int out_size, void* d_ws, size_t ws_size,
                              hipStream_t stream) {
    const void* x      = d_in[0];
    const void* mask   = d_in[1];
    const void* w_qk_s = d_in[2];
    const void* w_qk_q = d_in[3];
    const void* w_v    = d_in[4];
    const void* w_gate = d_in[5];
    const void* b_gate = d_in[6];
    const void* ln_g   = d_in[7];
    const void* ln_b   = d_in[8];
    const void* w1     = d_in[9];
    const void* b1     = d_in[10];
    const void* w2     = d_in[11];
    const void* b2     = d_in[12];
    const void* w_out  = d_in[13];
    const void* b_out  = d_in[14];
    float* out = (float*)d_out;

    char* ws = (char*)d_ws;
    size_t off = 0;
    auto nextp = [&](size_t bytes) {
        char* p = ws + off;
        off += (bytes + 255) & ~(size_t)255;
        return p;
    };
    const size_t QKV_ELEMS = (size_t)256 * 8 * 164 * 32;   // 10,747,904
    const size_t VT_ELEMS  = (size_t)256 * 8 * 32 * 176;   // 11,534,336
    int*      modes  = (int*)nextp(64);
    unsigned* maskb  = (unsigned*)nextp((size_t)256 * 6 * 4);
    __bf16* qws  = (__bf16*)nextp(QKV_ELEMS * 2);
    __bf16* kws  = (__bf16*)nextp(QKV_ELEMS * 2);
    __bf16* vtws = (__bf16*)nextp(VT_ELEMS * 2);
    __bf16* ohws = (__bf16*)nextp(QKV_ELEMS * 2);
    float*  gws  = (float*)nextp((size_t)2048 * 100 * 4 * 4);
    __bf16* Wts  = (__bf16*)nextp(768 * 256 * 2);
    __bf16* Wtq  = (__bf16*)nextp(768 * 256 * 2);
    __bf16* w1t  = (__bf16*)nextp(4 * 64 * 128 * 2);
    __bf16* w2t  = (__bf16*)nextp(4 * 112 * 64 * 2);
    __bf16* wot  = (__bf16*)nextp(256 * 256 * 2);
    __bf16* wsm  = (__bf16*)nextp(996 * 2);

    prep_kernel<<<1332, 256, 0, stream>>>(x, mask, w_qk_s, w_qk_q, w_v, w1, w2,
                                          w_out, w_gate, b_gate, ln_g, ln_b, b1,
                                          b2, b_out, modes, maskb,
                                          Wts, Wtq, w1t, w2t, wot, wsm);
    qkv_kernel<<<dim3(12, 256), 256, 0, stream>>>(x, Wts, Wtq, wsm, modes,
                                                  qws, kws, vtws, gws);
    attn_kernel<<<6144, 256, 0, stream>>>(qws, kws, vtws, gws, maskb,
                                          w1t, w2t, ohws);
    outproj_kernel<<<dim3(12, 256), 256, 0, stream>>>(ohws, wot, wsm, out);
}

// Round 6
// 484.459 us; speedup vs baseline: 1.2215x; 1.0123x over previous
//
#include <hip/hip_runtime.h>

typedef __bf16 bf16x8 __attribute__((ext_vector_type(8)));
typedef __bf16 bf16x4 __attribute__((ext_vector_type(4)));
typedef float  f32x4  __attribute__((ext_vector_type(4)));

__device__ __forceinline__ bf16x8 ldb8(const __bf16* p) {
    return *reinterpret_cast<const bf16x8*>(p);
}
__device__ __forceinline__ bf16x8 zero8() {
    bf16x8 z;
    #pragma unroll
    for (int i = 0; i < 8; i++) z[i] = (__bf16)0.f;
    return z;
}
// mode m: 0 = storage is bf16, 1 = storage is fp32
__device__ __forceinline__ __bf16 ldw(const void* p, int i, int m) {
    return m ? (__bf16)((const float*)p)[i] : ((const __bf16*)p)[i];
}
__device__ __forceinline__ bf16x8 ldx8(const void* p, size_t ei, int m) {
    if (m) {
        const float* f = (const float*)p + ei;
        f32x4 a = *reinterpret_cast<const f32x4*>(f);
        f32x4 b = *reinterpret_cast<const f32x4*>(f + 4);
        bf16x8 r;
        #pragma unroll
        for (int u = 0; u < 4; u++) { r[u] = (__bf16)a[u]; r[4 + u] = (__bf16)b[u]; }
        return r;
    }
    return ldb8((const __bf16*)p + ei);
}

// ---------------- prep: self-detect dtype + weights + mask bits ----------------
// grid 1332: blocks 0..1267 weight transpose/pad, blocks 1268..1331 maskb build.
// Bias fold: w1t[n][k==100] = b1[n]; w2t[n][k==50] = b2[n]  (augmented GEMM).
// maskb: [256 b][6 u32] bitmask; bits >=164 pre-set (masked).
__global__ __launch_bounds__(256) void prep_kernel(
    const void* x, const void* mask,
    const void* wqks, const void* wqkq, const void* wv, const void* w1,
    const void* w2, const void* wout, const void* wg, const void* bg,
    const void* lng, const void* lnb, const void* b1, const void* b2,
    const void* bout, int* modes, unsigned* maskb,
    __bf16* __restrict__ Wts, __bf16* __restrict__ Wtq,
    __bf16* __restrict__ w1t, __bf16* __restrict__ w2t,
    __bf16* __restrict__ wot, __bf16* __restrict__ wsm)
{
    __shared__ int sbad;
    const int t = threadIdx.x, bid = blockIdx.x;
    if (t == 0) sbad = 0;
    __syncthreads();
    // every block self-detects x dtype (8 KB scan, L2-hit)
    {
        const unsigned int* xw = (const unsigned int*)x;
        int bad = 0;
        for (int i = t; i < 2048; i += 256) {
            unsigned int w = xw[i];
            unsigned int el = (w >> 7) & 0xFF, eh = (w >> 23) & 0xFF;
            if (el >= 0x94 || el == 0xFF) bad++;
            if (eh >= 0x94 || eh == 0xFF) bad++;
        }
        if (bad) atomicAdd(&sbad, bad);
    }
    __syncthreads();
    const int m = (sbad > 64) ? 1 : 0;

    if (bid >= 1268) {
        // ---- mask blocks: detect mask width locally, build packed bits ----
        __shared__ int v32bad, v16bad;
        __shared__ unsigned mb[24];
        const int mbid = bid - 1268;                 // 0..63
        if (t == 0) { v32bad = 0; v16bad = 0; }
        if (t < 24) mb[t] = ((t % 6) == 5) ? 0xFFFFFFF0u : 0u;
        __syncthreads();
        const unsigned int* mw = (const unsigned int*)mask;
        int b32 = 0, b16 = 0;
        for (int i = t; i < 10496; i += 256) {
            unsigned int w = mw[i];
            if (!(w == 0u || w == 1u || w == 0x3F800000u)) b32++;
            unsigned int h0 = w & 0xFFFFu, h1 = w >> 16;
            if (!(h0 == 0u || h0 == 1u || h0 == 0x3F80u)) b16++;
            if (!(h1 == 0u || h1 == 1u || h1 == 0x3F80u)) b16++;
        }
        if (b32) atomicAdd(&v32bad, b32);
        if (b16) atomicAdd(&v16bad, b16);
        __syncthreads();
        const int mmode = (v32bad == 0) ? 0 : ((v16bad == 0) ? 2 : 1);
        if (mbid == 0 && t == 0) { modes[0] = m; modes[1] = mmode; }
        const int lo = mbid * 656;                   // 4 batches per block
        for (int i2 = t; i2 < 656; i2 += 256) {
            int i = lo + i2;
            int val;
            if (mmode == 0)      val = (((const int*)mask)[i] != 0);
            else if (mmode == 2) val = (((const unsigned short*)mask)[i] != 0);
            else                 val = (((const unsigned char*)mask)[i] != 0);
            if (val) {
                int ib = i2 / 164, jb = i2 - ib * 164;
                atomicOr(&mb[ib * 6 + (jb >> 5)], 1u << (jb & 31));
            }
        }
        __syncthreads();
        if (t < 24) maskb[mbid * 24 + t] = mb[t];
        return;
    }

    int i = bid * 256 + t;
    if (i < 196608) {
        int n = i >> 8, k = i & 255;
        __bf16 vs, vq;
        if (n < 512) { vs = ldw(wqks, k * 512 + n, m); vq = ldw(wqkq, k * 512 + n, m); }
        else         { vs = ldw(wv, k * 256 + (n - 512), m); vq = vs; }
        Wts[i] = vs; Wtq[i] = vq;
        return;
    }
    i -= 196608;
    if (i < 32768) {
        int e = i >> 13, r = i & 8191, n = r >> 7, k = r & 127;
        __bf16 v = (__bf16)0.f;
        if (n < 50) {
            if (k < 100)       v = ldw(w1, (e * 100 + k) * 50 + n, m);
            else if (k == 100) v = ldw(b1, e * 50 + n, m);
        }
        w1t[i] = v;
        return;
    }
    i -= 32768;
    if (i < 28672) {
        int e = i / 7168, r = i % 7168, n = r >> 6, k = r & 63;
        __bf16 v = (__bf16)0.f;
        if (n < 100) {
            if (k < 50)       v = ldw(w2, (e * 50 + k) * 100 + n, m);
            else if (k == 50) v = ldw(b2, e * 100 + n, m);
        }
        w2t[i] = v;
        return;
    }
    i -= 28672;
    if (i < 65536) {
        int n = i >> 8, k = i & 255;
        wot[i] = ldw(wout, k * 256 + n, m);
        return;
    }
    i -= 65536;
    if (i < 996) {
        __bf16 v;
        if (i < 128)      v = ldw(wg, i, m);
        else if (i < 132) v = ldw(bg, i - 128, m);
        else if (i < 136) v = ldw(lng, i - 132, m);
        else if (i < 140) v = ldw(lnb, i - 136, m);
        else if (i < 340) v = ldw(b1, i - 140, m);
        else if (i < 740) v = ldw(b2, i - 340, m);
        else              v = ldw(bout, i - 740, m);
        wsm[i] = v;
    }
}

// ---------------- qkv projection GEMM + fused gate (round-2 proven form) ----------------
// grid (12, B): x = mt(0..5) * 2 + half(0..1).  Block = 32 rows x 384 cols.
// V is written TRANSPOSED: vt[bh][d(32)][i stride 176] (only i<164 written).
__global__ __launch_bounds__(256, 2) void qkv_kernel(
    const void* __restrict__ x, const __bf16* __restrict__ Wts,
    const __bf16* __restrict__ Wtq, const __bf16* __restrict__ wsm,
    const int* __restrict__ modes,
    __bf16* __restrict__ q, __bf16* __restrict__ k, __bf16* __restrict__ vt,
    float* __restrict__ gates)
{
    __shared__ __bf16 xs[32][264];
    __shared__ float wgf[128];
    __shared__ float gcst[12];
    const int m = modes[0];
    const int b = blockIdx.y;
    const int mt = blockIdx.x >> 1;
    const int half = blockIdx.x & 1;
    const __bf16* Wt = (mt < 4) ? Wts : Wtq;
    const int rbase = (mt < 4) ? mt * 32 : 100 + (mt - 4) * 32;
    const int tid = threadIdx.x;

    if (tid < 128) wgf[tid] = (float)wsm[tid];
    if (tid < 12)  gcst[tid] = (float)wsm[128 + tid];
    for (int c = tid; c < 1024; c += 256) {
        int row = c >> 5, part = c & 31;
        bf16x8 val = ldx8(x, ((size_t)b * 164 + rbase + row) * 256 + part * 8, m);
        *reinterpret_cast<bf16x8*>(&xs[row][part * 8]) = val;
    }
    __syncthreads();

    // ---- fused gate (only half==0 computes) ----
    if (half == 0) {
        int jg = rbase * 8 + tid;
        int h = jg / 164;
        int j = jg - h * 164;
        if (j < 100) {
            const __bf16* xp = &xs[tid >> 3][(tid & 7) * 32];
            float g[4] = {gcst[0], gcst[1], gcst[2], gcst[3]};
            #pragma unroll
            for (int p = 0; p < 4; p++) {
                bf16x8 xv = ldb8(xp + p * 8);
                #pragma unroll
                for (int u = 0; u < 8; u++) {
                    float f = (float)xv[u];
                    #pragma unroll
                    for (int e = 0; e < 4; e++) g[e] += f * wgf[(p * 8 + u) * 4 + e];
                }
            }
            float mu = 0.25f * (g[0] + g[1] + g[2] + g[3]);
            float var = 0.25f * ((g[0]-mu)*(g[0]-mu) + (g[1]-mu)*(g[1]-mu) +
                                 (g[2]-mu)*(g[2]-mu) + (g[3]-mu)*(g[3]-mu));
            float is = rsqrtf(var + 1e-5f);
            float mx = -3.0e38f;
            #pragma unroll
            for (int e = 0; e < 4; e++) {
                g[e] = (g[e] - mu) * is * gcst[4 + e] + gcst[8 + e];
                mx = fmaxf(mx, g[e]);
            }
            float s = 0.f;
            #pragma unroll
            for (int e = 0; e < 4; e++) { g[e] = __expf(g[e] - mx); s += g[e]; }
            float inv = 1.f / s;
            float4 gv = make_float4(g[0]*inv, g[1]*inv, g[2]*inv, g[3]*inv);
            *reinterpret_cast<float4*>(&gates[((size_t)(b * 8 + h) * 100 + j) * 4]) = gv;
        }
    }

    const int w = tid >> 6, l = tid & 63, lr = l & 15, lc = l >> 4;
    f32x4 acc[2][6];
    #pragma unroll
    for (int ms = 0; ms < 2; ms++)
        #pragma unroll
        for (int nt = 0; nt < 6; nt++) acc[ms][nt] = (f32x4){0.f, 0.f, 0.f, 0.f};

    #pragma unroll
    for (int kt = 0; kt < 8; kt++) {
        bf16x8 a0 = ldb8(&xs[lr][kt * 32 + lc * 8]);
        bf16x8 a1 = ldb8(&xs[16 + lr][kt * 32 + lc * 8]);
        #pragma unroll
        for (int nt = 0; nt < 6; nt++) {
            bf16x8 bb = ldb8(Wt + (size_t)(half * 384 + w * 96 + nt * 16 + lr) * 256 + kt * 32 + lc * 8);
            acc[0][nt] = __builtin_amdgcn_mfma_f32_16x16x32_bf16(a0, bb, acc[0][nt], 0, 0, 0);
            acc[1][nt] = __builtin_amdgcn_mfma_f32_16x16x32_bf16(a1, bb, acc[1][nt], 0, 0, 0);
        }
    }
    #pragma unroll
    for (int ms = 0; ms < 2; ms++) {
        #pragma unroll
        for (int nt = 0; nt < 6; nt++) {
            int c = half * 384 + w * 96 + nt * 16 + lr;
            int i0 = rbase + ms * 16 + lc * 4;
            if (c < 512) {
                __bf16* dst; int ch;
                if (c < 256) { dst = q; ch = c; }
                else         { dst = k; ch = c - 256; }
                int hh = ch >> 5, d = ch & 31;
                #pragma unroll
                for (int r = 0; r < 4; r++) {
                    int i = i0 + r;
                    if (mt >= 4 || i < 100)
                        dst[(((size_t)b * 8 + hh) * 164 + i) * 32 + d] = (__bf16)acc[ms][nt][r];
                }
            } else {
                int ch = c - 512, hh = ch >> 5, d = ch & 31;
                if (mt >= 4 || i0 < 100) {
                    bf16x4 pv;
                    #pragma unroll
                    for (int r = 0; r < 4; r++) pv[r] = (__bf16)acc[ms][nt][r];
                    *reinterpret_cast<bf16x4*>(&vt[((size_t)(b * 8 + hh) * 32 + d) * 176 + i0]) = pv;
                }
            }
        }
    }
}

// ---------------- fused attention v10: ONE barrier, direct-global K, per-wave LDS ----
// flat grid 6144: xcd = flat&7, j = flat>>3, bh = ((j&255)<<3)|xcd, rt = j>>8
// LDS pool 19712 elems (39424 B), 4 blocks/CU:
//   Vt [0,6400)            Vt[32][200]  (cross-wave; the ONLY barrier protects this)
//   per-wave chunk WB = 6400 + w*3328:
//     reluS 16x136 @WB | h1 16x72 @WB+2176   -> P 16x200 @WB (overlays, same wave)
// No K staging: QK B-fragments are direct coalesced global loads (mask-protected).
__global__ __launch_bounds__(256, 4) void attn_kernel(
    const __bf16* __restrict__ qg, const __bf16* __restrict__ kg,
    const __bf16* __restrict__ vtg, const float* __restrict__ gatesg,
    const unsigned* __restrict__ maskbg, const __bf16* __restrict__ w1t,
    const __bf16* __restrict__ w2t, __bf16* __restrict__ ohg)
{
    __shared__ __align__(16) __bf16 lds[19712];
    const int flat = blockIdx.x;
    const int xcd = flat & 7, j5 = flat >> 3;
    const int bh = ((j5 & 255) << 3) | xcd;
    const int rt = j5 >> 8;
    const int b = bh >> 3, tid = threadIdx.x;
    const int w = tid >> 6, l = tid & 63, lr = l & 15, lc = l >> 4;
    const int m0 = w * 16;
    const int WB  = 6400 + w * 3328;   // per-wave chunk
    const int H1B = WB + 2176;
    const bool moe_wave = (rt * 64 + m0) < 100;

    // ---- T14: issue Vt loads into registers at entry (latency hides under QK) ----
    const __bf16* vtb = vtg + (size_t)bh * 32 * 176;
    bf16x8 vv0, vv1, vv2;
    {
        int c = tid;
        int row = c / 24, j0 = (c - row * 24) * 8;
        if (j0 < 164) {
            vv0 = ldb8(vtb + row * 176 + j0);
            if (j0 == 160) { vv0[4] = (__bf16)0.f; vv0[5] = (__bf16)0.f; vv0[6] = (__bf16)0.f; vv0[7] = (__bf16)0.f; }
        } else vv0 = zero8();
    }
    {
        int c = tid + 256;
        int row = c / 24, j0 = (c - row * 24) * 8;
        if (j0 < 164) {
            vv1 = ldb8(vtb + row * 176 + j0);
            if (j0 == 160) { vv1[4] = (__bf16)0.f; vv1[5] = (__bf16)0.f; vv1[6] = (__bf16)0.f; vv1[7] = (__bf16)0.f; }
        } else vv1 = zero8();
    }
    {
        int c = tid + 512;
        int row = c / 24, j0 = (c - row * 24) * 8;
        if (j0 < 164) {
            vv2 = ldb8(vtb + row * 176 + j0);
            if (j0 == 160) { vv2[4] = (__bf16)0.f; vv2[5] = (__bf16)0.f; vv2[6] = (__bf16)0.f; vv2[7] = (__bf16)0.f; }
        } else vv2 = zero8();
    }

    // ---- mask bits from packed words (uniform loads) ----
    const unsigned* mbp = maskbg + b * 6;
    unsigned mbits = 0;
    #pragma unroll
    for (int nt = 0; nt < 11; nt++)
        mbits |= ((mbp[nt >> 1] >> (((nt & 1) << 4) + lr)) & 1u) << nt;
    // Q row (direct global)
    int qrow = rt * 64 + m0 + lr; if (qrow > 163) qrow = 163;
    bf16x8 afq = ldb8(qg + ((size_t)bh * 164 + qrow) * 32 + lc * 8);

    // ---- QK^T with DIRECT GLOBAL K loads (coalesced 16B/lane; no LDS, no barrier) ----
    const __bf16* kbase = kg + (size_t)bh * 164 * 32;
    f32x4 raw[11];
    #pragma unroll
    for (int nt = 0; nt < 11; nt++) {
        int krow = nt * 16 + lr; if (krow > 163) krow = 163;
        bf16x8 kb = ldb8(kbase + (size_t)krow * 32 + lc * 8);
        f32x4 acc = {0.f, 0.f, 0.f, 0.f};
        acc = __builtin_amdgcn_mfma_f32_16x16x32_bf16(afq, kb, acc, 0, 0, 0);
        bool bad = (mbits >> nt) & 1;
        #pragma unroll
        for (int r = 0; r < 4; r++)
            raw[nt][r] = bad ? -1e30f : acc[r] * 0.0625f;
    }

    // ---- Vt LDS writes (global loads have landed under QK) ----
    {
        int c = tid;
        int row = c / 24, j0 = (c - row * 24) * 8;
        *reinterpret_cast<bf16x8*>(&lds[row * 200 + j0]) = vv0;
        c = tid + 256;
        row = c / 24; j0 = (c - row * 24) * 8;
        *reinterpret_cast<bf16x8*>(&lds[row * 200 + j0]) = vv1;
        c = tid + 512;
        row = c / 24; j0 = (c - row * 24) * 8;
        *reinterpret_cast<bf16x8*>(&lds[row * 200 + j0]) = vv2;
    }

    // ---- reluS write (wave-local chunk; col 100 = 1.0 bias row) ----
    if (moe_wave) {
        #pragma unroll
        for (int nt = 0; nt < 8; nt++) {
            int j = nt * 16 + lr;
            #pragma unroll
            for (int r = 0; r < 4; r++) {
                float v = raw[nt][r];
                v = (v < 0.f) ? 0.f : v;
                if (j >= 100) v = (j == 100) ? 1.f : 0.f;
                lds[WB + (lc * 4 + r) * 136 + j] = (__bf16)v;
            }
        }
    }

    // ---- MoE (all LDS wave-local; intra-wave DS ordering, no barriers) ----
    if (moe_wave) {
        const int gi0 = rt * 64 + m0 + lc * 4;
        for (int e = 0; e < 4; e++) {
            bf16x8 sa[4];
            #pragma unroll
            for (int kt = 0; kt < 4; kt++)
                sa[kt] = ldb8(&lds[WB + lr * 136 + kt * 32 + lc * 8]);
            #pragma unroll
            for (int nt = 0; nt < 4; nt++) {
                f32x4 acc = {0.f, 0.f, 0.f, 0.f};
                __builtin_amdgcn_s_setprio(1);
                #pragma unroll
                for (int kt = 0; kt < 4; kt++) {
                    bf16x8 bb = ldb8(w1t + (size_t)(e * 64 + nt * 16 + lr) * 128 + kt * 32 + lc * 8);
                    acc = __builtin_amdgcn_mfma_f32_16x16x32_bf16(sa[kt], bb, acc, 0, 0, 0);
                }
                __builtin_amdgcn_s_setprio(0);
                int n = nt * 16 + lr;
                #pragma unroll
                for (int r = 0; r < 4; r++) {
                    float v = acc[r];
                    if (v < 0.f) v = 0.f;
                    if (n == 50) v = 1.f;   // bias col for augmented GEMM2
                    lds[H1B + (lc * 4 + r) * 72 + n] = (__bf16)v;
                }
            }
            bf16x8 ha0 = ldb8(&lds[H1B + lr * 72 + lc * 8]);
            bf16x8 ha1 = ldb8(&lds[H1B + lr * 72 + 32 + lc * 8]);
            float gt[4];
            #pragma unroll
            for (int r = 0; r < 4; r++) {
                int gi = gi0 + r;
                gt[r] = (gi < 100) ? gatesg[((size_t)bh * 100 + gi) * 4 + e] : 0.f;
            }
            #pragma unroll
            for (int nt = 0; nt < 7; nt++) {
                f32x4 acc = {0.f, 0.f, 0.f, 0.f};
                __builtin_amdgcn_s_setprio(1);
                bf16x8 bb0 = ldb8(w2t + (size_t)(e * 112 + nt * 16 + lr) * 64 + lc * 8);
                acc = __builtin_amdgcn_mfma_f32_16x16x32_bf16(ha0, bb0, acc, 0, 0, 0);
                bf16x8 bb1 = ldb8(w2t + (size_t)(e * 112 + nt * 16 + lr) * 64 + 32 + lc * 8);
                acc = __builtin_amdgcn_mfma_f32_16x16x32_bf16(ha1, bb1, acc, 0, 0, 0);
                __builtin_amdgcn_s_setprio(0);
                #pragma unroll
                for (int r = 0; r < 4; r++) {
                    float v = acc[r];
                    if (v < 0.f) v = 0.f;
                    raw[nt][r] += v * gt[r];
                }
            }
        }
    }

    // ---- in-register softmax; write probs P into own chunk (overlays reluS/h1) ----
    #pragma unroll
    for (int r = 0; r < 4; r++) {
        float m2 = raw[0][r];
        #pragma unroll
        for (int nt = 1; nt < 11; nt++) m2 = fmaxf(m2, raw[nt][r]);
        m2 = fmaxf(m2, __shfl_xor(m2, 1, 64));
        m2 = fmaxf(m2, __shfl_xor(m2, 2, 64));
        m2 = fmaxf(m2, __shfl_xor(m2, 4, 64));
        m2 = fmaxf(m2, __shfl_xor(m2, 8, 64));
        float s2 = 0.f;
        #pragma unroll
        for (int nt = 0; nt < 11; nt++) {
            float ev = __expf(raw[nt][r] - m2);
            raw[nt][r] = ev;
            s2 += ev;
        }
        s2 += __shfl_xor(s2, 1, 64);
        s2 += __shfl_xor(s2, 2, 64);
        s2 += __shfl_xor(s2, 4, 64);
        s2 += __shfl_xor(s2, 8, 64);
        float inv = (s2 > 0.f) ? 1.f / s2 : 0.f;
        #pragma unroll
        for (int nt = 0; nt < 11; nt++)
            lds[WB + (lc * 4 + r) * 200 + nt * 16 + lr] = (__bf16)(raw[nt][r] * inv);
        lds[WB + (lc * 4 + r) * 200 + 176 + lr] = (__bf16)0.f;
    }
    __syncthreads();   // the ONE barrier: Vt (cross-wave) fully staged

    // ---- O^T = V^T @ P^T ----
    int gi = rt * 64 + m0 + lr;
    #pragma unroll
    for (int nt = 0; nt < 2; nt++) {
        f32x4 acc = {0.f, 0.f, 0.f, 0.f};
        __builtin_amdgcn_s_setprio(1);
        #pragma unroll
        for (int kt = 0; kt < 6; kt++) {
            bf16x8 va = ldb8(&lds[(nt * 16 + lr) * 200 + kt * 32 + lc * 8]);
            bf16x8 pb = ldb8(&lds[WB + lr * 200 + kt * 32 + lc * 8]);
            acc = __builtin_amdgcn_mfma_f32_16x16x32_bf16(va, pb, acc, 0, 0, 0);
        }
        __builtin_amdgcn_s_setprio(0);
        if (gi < 164) {
            bf16x4 ov;
            #pragma unroll
            for (int r = 0; r < 4; r++) ov[r] = (__bf16)acc[r];
            *reinterpret_cast<bf16x4*>(&ohg[((size_t)bh * 164 + gi) * 32 + nt * 16 + lc * 4]) = ov;
        }
    }
}

// ---------------- output projection (round-2 proven form, writes fp32) ----------------
__global__ __launch_bounds__(256) void outproj_kernel(
    const __bf16* __restrict__ oh, const __bf16* __restrict__ wot,
    const __bf16* __restrict__ wsm, float* __restrict__ out)
{
    const __bf16* bout = wsm + 740;
    const int b = blockIdx.y;
    const int mt = blockIdx.x >> 2;
    const int ntile = blockIdx.x & 3;
    const int tid = threadIdx.x;
    const int w = tid >> 6, l = tid & 63, lr = l & 15, lc = l >> 4;
    int row = mt * 64 + w * 16 + lr; if (row > 163) row = 163;
    f32x4 acc[4];
    #pragma unroll
    for (int nt = 0; nt < 4; nt++) acc[nt] = (f32x4){0.f, 0.f, 0.f, 0.f};
    #pragma unroll
    for (int kt = 0; kt < 8; kt++) {
        bf16x8 a = ldb8(oh + (((size_t)b * 8 + kt) * 164 + row) * 32 + lc * 8);
        #pragma unroll
        for (int nt = 0; nt < 4; nt++) {
            bf16x8 bb = ldb8(wot + (size_t)(ntile * 64 + nt * 16 + lr) * 256 + kt * 32 + lc * 8);
            acc[nt] = __builtin_amdgcn_mfma_f32_16x16x32_bf16(a, bb, acc[nt], 0, 0, 0);
        }
    }
    #pragma unroll
    for (int nt = 0; nt < 4; nt++) {
        int n = ntile * 64 + nt * 16 + lr;
        float bias = (float)bout[n];
        #pragma unroll
        for (int r = 0; r < 4; r++) {
            int i = mt * 64 + w * 16 + lc * 4 + r;
            if (i < 164)
                out[((size_t)b * 164 + i) * 256 + n] = acc[nt][r] + bias;
        }
    }
}

extern "C" void kernel_launch(void* const* d_in, const int* in_sizes, int n_in,
                              void* d_out, int out_size, void* d_ws, size_t ws_size,
                              hipStream_t stream) {
    const void* x      = d_in[0];
    const void* mask   = d_in[1];
    const void* w_qk_s = d_in[2];
    const void* w_qk_q = d_in[3];
    const void* w_v    = d_in[4];
    const void* w_gate = d_in[5];
    const void* b_gate = d_in[6];
    const void* ln_g   = d_in[7];
    const void* ln_b   = d_in[8];
    const void* w1     = d_in[9];
    const void* b1     = d_in[10];
    const void* w2     = d_in[11];
    const void* b2     = d_in[12];
    const void* w_out  = d_in[13];
    const void* b_out  = d_in[14];
    float* out = (float*)d_out;

    char* ws = (char*)d_ws;
    size_t off = 0;
    auto nextp = [&](size_t bytes) {
        char* p = ws + off;
        off += (bytes + 255) & ~(size_t)255;
        return p;
    };
    const size_t QKV_ELEMS = (size_t)256 * 8 * 164 * 32;   // 10,747,904
    const size_t VT_ELEMS  = (size_t)256 * 8 * 32 * 176;   // 11,534,336
    int*      modes  = (int*)nextp(64);
    unsigned* maskb  = (unsigned*)nextp((size_t)256 * 6 * 4);
    __bf16* qws  = (__bf16*)nextp(QKV_ELEMS * 2);
    __bf16* kws  = (__bf16*)nextp(QKV_ELEMS * 2);
    __bf16* vtws = (__bf16*)nextp(VT_ELEMS * 2);
    __bf16* ohws = (__bf16*)nextp(QKV_ELEMS * 2);
    float*  gws  = (float*)nextp((size_t)2048 * 100 * 4 * 4);
    __bf16* Wts  = (__bf16*)nextp(768 * 256 * 2);
    __bf16* Wtq  = (__bf16*)nextp(768 * 256 * 2);
    __bf16* w1t  = (__bf16*)nextp(4 * 64 * 128 * 2);
    __bf16* w2t  = (__bf16*)nextp(4 * 112 * 64 * 2);
    __bf16* wot  = (__bf16*)nextp(256 * 256 * 2);
    __bf16* wsm  = (__bf16*)nextp(996 * 2);

    prep_kernel<<<1332, 256, 0, stream>>>(x, mask, w_qk_s, w_qk_q, w_v, w1, w2,
                                          w_out, w_gate, b_gate, ln_g, ln_b, b1,
                                          b2, b_out, modes, maskb,
                                          Wts, Wtq, w1t, w2t, wot, wsm);
    qkv_kernel<<<dim3(12, 256), 256, 0, stream>>>(x, Wts, Wtq, wsm, modes,
                                                  qws, kws, vtws, gws);
    attn_kernel<<<6144, 256, 0, stream>>>(qws, kws, vtws, gws, maskb,
                                          w1t, w2t, ohws);
    outproj_kernel<<<dim3(12, 256), 256, 0, stream>>>(ohws, wot, wsm, out);
}